// Round 1
// baseline (823.512 us; speedup 1.0000x reference)
//
#include <hip/hip_runtime.h>
#include <stdint.h>
#include <math.h>

#define INF __builtin_inff()

typedef __attribute__((ext_vector_type(4))) float f32x4;
typedef __attribute__((ext_vector_type(2))) float f32x2;
typedef __attribute__((ext_vector_type(8))) short s16x8;

// ---- min/max + absmax scalar slots (order-preserving uint encoding) ----
#define S_XMN 0
#define S_XMX 1
#define S_T1MN 2
#define S_T1MX 3
#define S_T4MN 4
#define S_T4MX 5
#define S_T7MN 6
#define S_T7MX 7
#define S_CVMN 8
#define S_CVMX 9
#define S_BNMN 10
#define S_BNMX 11
#define S_SIMN 12
#define S_SIMX 13
#define S_T18MN 14
#define S_T18MX 15
#define S_W1 16
#define S_W2 17
#define S_DW 18
#define NSLOT 19

#define NTOT 16777216L   // 32*1024*512
#define TP 1056          // padded T for depthwise conv (16 + 1024 + 16)

__device__ __forceinline__ unsigned enc(float f) {
  unsigned u = __float_as_uint(f);
  return (u & 0x80000000u) ? ~u : (u | 0x80000000u);
}
__device__ __forceinline__ float dec(unsigned k) {
  return (k & 0x80000000u) ? __uint_as_float(k & 0x7FFFFFFFu) : __uint_as_float(~k);
}

struct FQ { float s, zp; };

// per-tensor affine observer: mn=min(min,0), mx=max(max,0); matches jnp exactly
__device__ __forceinline__ FQ fq_params(float mn_t, float mx_t) {
  float mn = fminf(mn_t, 0.0f), mx = fmaxf(mx_t, 0.0f);
  FQ p;
  p.s = fmaxf((mx - mn) / 255.0f, 1e-8f);
  p.zp = -128.0f - rintf(mn / p.s);
  return p;
}
__device__ __forceinline__ float fq_apply(float x, FQ p) {
  float q = rintf(x / p.s) + p.zp;
  q = fminf(fmaxf(q, -128.0f), 127.0f);
  return (q - p.zp) * p.s;
}
// returns integer-valued (q - zp) in [-255,255]
__device__ __forceinline__ float fq_qmz(float x, FQ p) {
  float q = rintf(x / p.s) + p.zp;
  q = fminf(fmaxf(q, -128.0f), 127.0f);
  return q - p.zp;
}
// double-fq params: second fq's observer sees fq1(min), fq1(max) (monotone)
__device__ __forceinline__ void fq_pair(const unsigned* slots, int idx, FQ& p1, FQ& p2) {
  float mn = dec(slots[idx]), mx = dec(slots[idx + 1]);
  p1 = fq_params(mn, mx);
  float ymn = fq_apply(mn, p1), ymx = fq_apply(mx, p1);
  p2 = fq_params(ymn, ymx);
}
__device__ __forceinline__ unsigned short to_bf16(float v) {  // exact for small ints
  return (unsigned short)(__float_as_uint(v) >> 16);
}
__device__ __forceinline__ float from_bf16(unsigned short u) {
  return __uint_as_float(((unsigned)u) << 16);
}

__device__ __forceinline__ void mm_block_atomic(float mn, float mx, unsigned* smn, unsigned* smx) {
#pragma unroll
  for (int o = 32; o > 0; o >>= 1) {
    mn = fminf(mn, __shfl_down(mn, o, 64));
    mx = fmaxf(mx, __shfl_down(mx, o, 64));
  }
  __shared__ float rmn[16], rmx[16];
  int lane = threadIdx.x & 63, wid = threadIdx.x >> 6;
  int nw = blockDim.x >> 6;
  __syncthreads();
  if (lane == 0) { rmn[wid] = mn; rmx[wid] = mx; }
  __syncthreads();
  if (threadIdx.x == 0) {
    for (int i = 1; i < nw; ++i) { mn = fminf(mn, rmn[i]); mx = fmaxf(mx, rmx[i]); }
    atomicMin(smn, enc(mn));
    atomicMax(smx, enc(mx));
  }
}

__global__ void k_init(unsigned* __restrict__ slots) {
  int i = threadIdx.x;
  if (i < NSLOT) {
    unsigned v;
    if (i < 16) v = (i & 1) ? enc(-INF) : enc(INF);  // even slot=min(init +inf), odd=max(init -inf)
    else v = enc(0.0f);                               // absmax slots
    slots[i] = v;
  }
}

__global__ __launch_bounds__(256) void k_redmm(const float* __restrict__ x, unsigned* __restrict__ slots) {
  long i = ((long)blockIdx.x * 256 + threadIdx.x) * 4;
  const long stride = (long)2048 * 256 * 4;
  float mn = INF, mx = -INF;
  for (; i < NTOT; i += stride) {
    f32x4 v = *(const f32x4*)(x + i);
    mn = fminf(mn, fminf(fminf(v.x, v.y), fminf(v.z, v.w)));
    mx = fmaxf(mx, fmaxf(fmaxf(v.x, v.y), fmaxf(v.z, v.w)));
  }
  mm_block_atomic(mn, mx, slots + S_XMN, slots + S_XMX);
}

// blocks: [0,2048)=w1, [2048,3072)=w2, [3072,3134)=dw_w
__global__ __launch_bounds__(256) void k_wabs(const float* __restrict__ w1, const float* __restrict__ w2,
                                              const float* __restrict__ dw, unsigned* __restrict__ slots) {
  int b = blockIdx.x;
  const float* p; int slot; long base;
  if (b < 2048) { p = w1; slot = S_W1; base = (long)b * 256; }
  else if (b < 3072) { p = w2; slot = S_W2; base = (long)(b - 2048) * 256; }
  else { p = dw; slot = S_DW; base = (long)(b - 3072) * 256; }
  float v = fabsf(p[base + threadIdx.x]);
#pragma unroll
  for (int o = 32; o > 0; o >>= 1) v = fmaxf(v, __shfl_down(v, o, 64));
  __shared__ float r[4];
  int lane = threadIdx.x & 63, wid = threadIdx.x >> 6;
  if (lane == 0) r[wid] = v;
  __syncthreads();
  if (threadIdx.x == 0) {
    v = fmaxf(fmaxf(r[0], r[1]), fmaxf(r[2], r[3]));
    atomicMax(slots + slot, enc(v));
  }
}

// symmetric weight quant: store integer q as bf16 (w1,w2) / fp32 (dw)
__global__ __launch_bounds__(256) void k_wq(const float* __restrict__ w1, const float* __restrict__ w2,
    const float* __restrict__ dw, unsigned short* __restrict__ w1q, unsigned short* __restrict__ w2q,
    float* __restrict__ dwq, const unsigned* __restrict__ slots) {
  int b = blockIdx.x;
  if (b < 2048) {
    float s = fmaxf(dec(slots[S_W1]) / 127.0f, 1e-8f);
    long i = (long)b * 256 + threadIdx.x;
    float q = fminf(fmaxf(rintf(w1[i] / s), -128.0f), 127.0f);
    w1q[i] = to_bf16(q);
  } else if (b < 3072) {
    float s = fmaxf(dec(slots[S_W2]) / 127.0f, 1e-8f);
    long i = (long)(b - 2048) * 256 + threadIdx.x;
    float q = fminf(fmaxf(rintf(w2[i] / s), -128.0f), 127.0f);
    w2q[i] = to_bf16(q);
  } else {
    float s = fmaxf(dec(slots[S_DW]) / 127.0f, 1e-8f);
    long i = (long)(b - 3072) * 256 + threadIdx.x;
    float q = fminf(fmaxf(rintf(dw[i] / s), -128.0f), 127.0f);
    dwq[i] = q;
  }
}

__device__ __forceinline__ float block_sum256(float v, float* sh) {
#pragma unroll
  for (int o = 32; o > 0; o >>= 1) v += __shfl_down(v, o, 64);
  int lane = threadIdx.x & 63, wid = threadIdx.x >> 6;
  __syncthreads();
  if (lane == 0) sh[wid] = v;
  __syncthreads();
  return sh[0] + sh[1] + sh[2] + sh[3];
}

// L1 layernorm: fq0(x) -> -mean -> /(L1/F + 1e-5) -> *scale+bias ; track mm(t1)
__global__ __launch_bounds__(256) void k_ln(const float* __restrict__ x, const float* __restrict__ lns,
    const float* __restrict__ lnb, float* __restrict__ t1, unsigned* __restrict__ slots) {
  __shared__ float sh[4];
  FQ p0 = fq_params(dec(slots[S_XMN]), dec(slots[S_XMX]));
  int c = threadIdx.x * 2;
  f32x2 sc = *(const f32x2*)(lns + c);
  f32x2 bi = *(const f32x2*)(lnb + c);
  float lmn = INF, lmx = -INF;
  for (int rr = 0; rr < 16; ++rr) {
    long row = (long)blockIdx.x * 16 + rr;
    const float* xr = x + row * 512;
    f32x2 xv = *(const f32x2*)(xr + c);
    float a0 = fq_apply(xv.x, p0), a1 = fq_apply(xv.y, p0);
    float mean = block_sum256(a0 + a1, sh) / 512.0f;
    a0 -= mean; a1 -= mean;
    float denom = block_sum256(fabsf(a0) + fabsf(a1), sh) / 512.0f + 1e-5f;
    a0 = (a0 / denom) * sc.x + bi.x;
    a1 = (a1 / denom) * sc.y + bi.y;
    f32x2 o; o.x = a0; o.y = a1;
    *(f32x2*)(t1 + row * 512 + c) = o;
    lmn = fminf(lmn, fminf(a0, a1));
    lmx = fmaxf(lmx, fmaxf(a0, a1));
  }
  mm_block_atomic(lmn, lmx, slots + S_T1MN, slots + S_T1MX);
}

// t1 -> double-fq -> (q - zp2) as integer bf16 (GEMM1 A-matrix)
__global__ __launch_bounds__(256) void k_qa(const float* __restrict__ t1, unsigned short* __restrict__ A1,
                                            const unsigned* __restrict__ slots) {
  FQ p1, p2; fq_pair(slots, S_T1MN, p1, p2);
  long i = ((long)blockIdx.x * 256 + threadIdx.x) * 8;
  const long stride = (long)2048 * 256 * 8;
  for (; i < NTOT; i += stride) {
    f32x4 v0 = *(const f32x4*)(t1 + i);
    f32x4 v1 = *(const f32x4*)(t1 + i + 4);
    s16x8 o;
#pragma unroll
    for (int j = 0; j < 4; ++j) o[j] = (short)to_bf16(fq_qmz(fq_apply(v0[j], p1), p2));
#pragma unroll
    for (int j = 0; j < 4; ++j) o[j + 4] = (short)to_bf16(fq_qmz(fq_apply(v1[j], p1), p2));
    *(s16x8*)(A1 + i) = o;
  }
}

// bf16-integer MFMA GEMM: A[M,512] k-major, Bm[N,512] k-major (both integer-valued)
// C = (sAct*sW)*acc + bias; tracks mm of C.  M=32768, K=512 fixed; N=1024/512.
__global__ __launch_bounds__(256) void k_gemm(const unsigned short* __restrict__ A,
    const unsigned short* __restrict__ Bm, const float* __restrict__ bias,
    float* __restrict__ C, int N, unsigned* __restrict__ slots, int mmIdx, int wIdx, int omIdx) {
  __shared__ __align__(16) unsigned short lA[128 * 64];
  __shared__ __align__(16) unsigned short lB[128 * 64];
  FQ p1, p2; fq_pair(slots, mmIdx, p1, p2);
  float sw = fmaxf(dec(slots[wIdx]) / 127.0f, 1e-8f);
  float sAB = p2.s * sw;
  int tid = threadIdx.x;
  int m0 = blockIdx.y * 128, n0 = blockIdx.x * 128;
  int lane = tid & 63, wid = tid >> 6;
  int wm = (wid >> 1) * 64, wn = (wid & 1) * 64;
  const f32x4 fz = {0.0f, 0.0f, 0.0f, 0.0f};
  f32x4 acc[4][4];
#pragma unroll
  for (int mi = 0; mi < 4; ++mi)
#pragma unroll
    for (int ni = 0; ni < 4; ++ni) acc[mi][ni] = fz;
  int sr = tid >> 1;              // staging row (0..127)
  int scu = (tid & 1) * 32;       // staging col base (ushorts)
  int swz = (sr & 7) * 8;         // XOR swizzle (8-ushort = 16B granules)
  const unsigned short* Ag = A + (long)(m0 + sr) * 512 + scu;
  const unsigned short* Bg = Bm + (long)(n0 + sr) * 512 + scu;
  int fr = lane & 15;
  int fc = (lane >> 4) * 8;
  for (int kt = 0; kt < 8; ++kt) {
    s16x8 ra[4], rb[4];
#pragma unroll
    for (int j = 0; j < 4; ++j) {
      ra[j] = *(const s16x8*)(Ag + kt * 64 + j * 8);
      rb[j] = *(const s16x8*)(Bg + kt * 64 + j * 8);
    }
    __syncthreads();
#pragma unroll
    for (int j = 0; j < 4; ++j) {
      *(s16x8*)&lA[sr * 64 + ((scu + j * 8) ^ swz)] = ra[j];
      *(s16x8*)&lB[sr * 64 + ((scu + j * 8) ^ swz)] = rb[j];
    }
    __syncthreads();
#pragma unroll
    for (int ks = 0; ks < 2; ++ks) {
      s16x8 af[4], bfv[4];
#pragma unroll
      for (int mi = 0; mi < 4; ++mi) {
        int r = wm + mi * 16 + fr;
        af[mi] = *(const s16x8*)&lA[r * 64 + ((ks * 32 + fc) ^ ((r & 7) * 8))];
      }
#pragma unroll
      for (int ni = 0; ni < 4; ++ni) {
        int r = wn + ni * 16 + fr;
        bfv[ni] = *(const s16x8*)&lB[r * 64 + ((ks * 32 + fc) ^ ((r & 7) * 8))];
      }
#pragma unroll
      for (int mi = 0; mi < 4; ++mi)
#pragma unroll
        for (int ni = 0; ni < 4; ++ni)
          acc[mi][ni] = __builtin_amdgcn_mfma_f32_16x16x32_bf16(af[mi], bfv[ni], acc[mi][ni], 0, 0, 0);
    }
  }
  float lmn = INF, lmx = -INF;
  int rb0 = m0 + wm + ((lane >> 4) << 2);
  int cb0 = n0 + wn + (lane & 15);
#pragma unroll
  for (int mi = 0; mi < 4; ++mi) {
#pragma unroll
    for (int ni = 0; ni < 4; ++ni) {
      int col = cb0 + ni * 16;
      float bv = bias[col];
#pragma unroll
      for (int r = 0; r < 4; ++r) {
        int rowi = rb0 + mi * 16 + r;
        float v = sAB * acc[mi][ni][r] + bv;
        C[(long)rowi * N + col] = v;
        lmn = fminf(lmn, v); lmx = fmaxf(lmx, v);
      }
    }
  }
  mm_block_atomic(lmn, lmx, slots + omIdx, slots + omIdx + 1);
}

// GLU: a,g = split(fq2(t4)); t7 = a*sigmoid(g); mm(t7)
__global__ __launch_bounds__(256) void k_glu(const float* __restrict__ t4, float* __restrict__ t7,
                                             unsigned* __restrict__ slots) {
  FQ p1, p2; fq_pair(slots, S_T4MN, p1, p2);
  long i = ((long)blockIdx.x * 256 + threadIdx.x) * 4;
  const long stride = (long)2048 * 256 * 4;
  float lmn = INF, lmx = -INF;
  for (; i < NTOT; i += stride) {
    long r = i >> 9;
    int c = (int)(i & 511);
    const float* pa = t4 + r * 1024 + c;
    f32x4 av = *(const f32x4*)pa;
    f32x4 gv = *(const f32x4*)(pa + 512);
    f32x4 o;
#pragma unroll
    for (int j = 0; j < 4; ++j) {
      float a = fq_apply(fq_apply(av[j], p1), p2);
      float g = fq_apply(fq_apply(gv[j], p1), p2);
      float y = a * (1.0f / (1.0f + expf(-g)));
      o[j] = y;
      lmn = fminf(lmn, y); lmx = fmaxf(lmx, y);
    }
    *(f32x4*)(t7 + i) = o;
  }
  mm_block_atomic(lmn, lmx, slots + S_T7MN, slots + S_T7MX);
}

// quantize t7 with pair(C,D) and transpose [B,T,F]->[B,F,TP] (bf16 ints, zero pads)
__global__ void k_qt(const float* __restrict__ t7, unsigned short* __restrict__ vT,
                     const unsigned* __restrict__ slots) {
  FQ p1, p2; fq_pair(slots, S_T7MN, p1, p2);
  int b = blockIdx.z, fg = blockIdx.y, tq = blockIdx.x;
  int f = fg * 64 + threadIdx.x;
  const float* in = t7 + (long)b * 1024 * 512 + f;
  unsigned short* orow = vT + (long)(b * 512 + f) * TP + 16;
  for (int tt = 0; tt < 256; tt += 8) {
    int tbase = tq * 256 + tt;
    s16x8 o;
#pragma unroll
    for (int j = 0; j < 8; ++j) {
      float v = in[(long)(tbase + j) * 512];
      o[j] = (short)to_bf16(fq_qmz(fq_apply(v, p1), p2));
    }
    *(s16x8*)(orow + tbase) = o;
  }
  s16x8 z = {0, 0, 0, 0, 0, 0, 0, 0};
  if (tq == 0) { *(s16x8*)(orow - 16) = z; *(s16x8*)(orow - 8) = z; }
  if (tq == 3) { *(s16x8*)(orow + 1024) = z; *(s16x8*)(orow + 1032) = z; }
}

// depthwise conv over time (K=31, pad 15), exact integer dot * (sD*sDW) + bias; mm out
__global__ __launch_bounds__(256) void k_conv(const unsigned short* __restrict__ vT,
    const float* __restrict__ dwq, const float* __restrict__ dwb,
    float* __restrict__ out, unsigned* __restrict__ slots) {
  FQ pC, pD; fq_pair(slots, S_T7MN, pC, pD);
  float sdw = fmaxf(dec(slots[S_DW]) / 127.0f, 1e-8f);
  float scv = pD.s * sdw;
  int b = blockIdx.y;
  int f = blockIdx.x * 8 + (threadIdx.x >> 5);
  int tbase = (threadIdx.x & 31) * 32;
  float w[31];
#pragma unroll
  for (int k = 0; k < 31; ++k) w[k] = dwq[f * 31 + k];
  float bias = dwb[f];
  const unsigned short* row = vT + (long)(b * 512 + f) * TP + 16;
  float* orow = out + (long)(b * 512 + f) * 1024;
  float lmn = INF, lmx = -INF;
  for (int half = 0; half < 2; ++half) {
    int t0 = tbase + half * 16;
    float win[48];
#pragma unroll
    for (int cch = 0; cch < 6; ++cch) {
      s16x8 u = *(const s16x8*)(row + t0 - 16 + cch * 8);
#pragma unroll
      for (int j = 0; j < 8; ++j) win[cch * 8 + j] = from_bf16((unsigned short)u[j]);
    }
#pragma unroll
    for (int tt = 0; tt < 16; tt += 4) {
      f32x4 o;
#pragma unroll
      for (int q = 0; q < 4; ++q) {
        float acc = 0.0f;
#pragma unroll
        for (int k = 0; k < 31; ++k) acc += win[tt + q + 1 + k] * w[k];
        float v = scv * acc + bias;
        o[q] = v;
        lmn = fminf(lmn, v); lmx = fmaxf(lmx, v);
      }
      *(f32x4*)(orow + t0 + tt) = o;
    }
  }
  mm_block_atomic(lmn, lmx, slots + S_CVMN, slots + S_CVMX);
}

// batchnorm (eval), layout [B,F,T]; in = fq2(convout); mm out
__global__ __launch_bounds__(256) void k_bn(const float* __restrict__ in,
    const float* __restrict__ gm, const float* __restrict__ bt,
    const float* __restrict__ mu, const float* __restrict__ vr,
    float* __restrict__ out, unsigned* __restrict__ slots) {
  FQ p1, p2; fq_pair(slots, S_CVMN, p1, p2);
  long i = ((long)blockIdx.x * 256 + threadIdx.x) * 4;
  const long stride = (long)2048 * 256 * 4;
  float lmn = INF, lmx = -INF;
  for (; i < NTOT; i += stride) {
    int f = (int)((i >> 10) & 511);
    float g = gm[f] / sqrtf(vr[f] + 1e-5f);
    float m = mu[f], be = bt[f];
    f32x4 v = *(const f32x4*)(in + i);
    f32x4 o;
#pragma unroll
    for (int j = 0; j < 4; ++j) {
      float y = fq_apply(fq_apply(v[j], p1), p2);
      float r2 = (y - m) * g + be;
      o[j] = r2;
      lmn = fminf(lmn, r2); lmx = fmaxf(lmx, r2);
    }
    *(f32x4*)(out + i) = o;
  }
  mm_block_atomic(lmn, lmx, slots + S_BNMN, slots + S_BNMX);
}

__global__ __launch_bounds__(256) void k_silu(const float* __restrict__ in, float* __restrict__ out,
                                              unsigned* __restrict__ slots) {
  FQ p1, p2; fq_pair(slots, S_BNMN, p1, p2);
  long i = ((long)blockIdx.x * 256 + threadIdx.x) * 4;
  const long stride = (long)2048 * 256 * 4;
  float lmn = INF, lmx = -INF;
  for (; i < NTOT; i += stride) {
    f32x4 v = *(const f32x4*)(in + i);
    f32x4 o;
#pragma unroll
    for (int j = 0; j < 4; ++j) {
      float y = fq_apply(fq_apply(v[j], p1), p2);
      float r2 = y * (1.0f / (1.0f + expf(-y)));
      o[j] = r2;
      lmn = fminf(lmn, r2); lmx = fmaxf(lmx, r2);
    }
    *(f32x4*)(out + i) = o;
  }
  mm_block_atomic(lmn, lmx, slots + S_SIMN, slots + S_SIMX);
}

// quantize silu-out with pair(I,J) and transpose [B,F,T]->[B,T,F] (GEMM2 A-matrix)
__global__ void k_q2t(const float* __restrict__ si, unsigned short* __restrict__ A2,
                      const unsigned* __restrict__ slots) {
  FQ p1, p2; fq_pair(slots, S_SIMN, p1, p2);
  int b = blockIdx.z;
  int t = blockIdx.y * 64 + threadIdx.x;
  int fc0 = blockIdx.x * 128;
  const float* in = si + (long)b * 512 * 1024 + t;
  unsigned short* orow = A2 + (long)(b * 1024 + t) * 512;
  for (int fc = 0; fc < 128; fc += 8) {
    int f = fc0 + fc;
    s16x8 o;
#pragma unroll
    for (int j = 0; j < 8; ++j) {
      float v = in[(long)(f + j) * 1024];
      o[j] = (short)to_bf16(fq_qmz(fq_apply(v, p1), p2));
    }
    *(s16x8*)(orow + f) = o;
  }
}

__global__ __launch_bounds__(256) void k_final(const float* __restrict__ t18, float* __restrict__ out,
                                               const unsigned* __restrict__ slots) {
  FQ p = fq_params(dec(slots[S_T18MN]), dec(slots[S_T18MX]));
  long i = ((long)blockIdx.x * 256 + threadIdx.x) * 4;
  const long stride = (long)2048 * 256 * 4;
  for (; i < NTOT; i += stride) {
    f32x4 v = *(const f32x4*)(t18 + i);
    f32x4 o;
#pragma unroll
    for (int j = 0; j < 4; ++j) o[j] = fq_apply(v[j], p);
    *(f32x4*)(out + i) = o;
  }
}

extern "C" void kernel_launch(void* const* d_in, const int* in_sizes, int n_in,
                              void* d_out, int out_size, void* d_ws, size_t ws_size,
                              hipStream_t stream) {
  const float* x   = (const float*)d_in[0];
  const float* lns = (const float*)d_in[1];
  const float* lnb = (const float*)d_in[2];
  const float* w1  = (const float*)d_in[3];
  const float* b1  = (const float*)d_in[4];
  const float* dw  = (const float*)d_in[5];
  const float* dwb = (const float*)d_in[6];
  const float* gm  = (const float*)d_in[7];
  const float* bt  = (const float*)d_in[8];
  const float* mu  = (const float*)d_in[9];
  const float* vr  = (const float*)d_in[10];
  const float* w2  = (const float*)d_in[11];
  const float* b2  = (const float*)d_in[12];
  float* out = (float*)d_out;
  char* ws = (char*)d_ws;

  // workspace layout (aliased lifetimes):
  //  [0,134MB)   : t1 (first half) -> t4 (full) ; [67,134MB): bnout -> t18
  //  [134,201MB) : t7 -> convout -> siluout
  //  [201,235.6) : A1 -> vT (padded) -> A2
  //  then weights + scalar slots
  const size_t OFF_B = 134217728;
  const size_t OFF_D = OFF_B + 67108864;
  const size_t OFF_W = OFF_D + 34603008;
  const size_t NEED = OFF_W + 1048576 + 524288 + 63488 + 256;
  if (ws_size < NEED) return;

  float* t1    = (float*)ws;
  float* t4    = (float*)ws;
  float* half2 = (float*)(ws + 67108864);
  float* bufB  = (float*)(ws + OFF_B);
  unsigned short* bufD = (unsigned short*)(ws + OFF_D);
  unsigned short* w1q = (unsigned short*)(ws + OFF_W);
  unsigned short* w2q = (unsigned short*)(ws + OFF_W + 1048576);
  float* dwq = (float*)(ws + OFF_W + 1048576 + 524288);
  unsigned* slots = (unsigned*)(ws + OFF_W + 1048576 + 524288 + 63488);

  k_init<<<1, 32, 0, stream>>>(slots);
  k_redmm<<<2048, 256, 0, stream>>>(x, slots);
  k_wabs<<<3134, 256, 0, stream>>>(w1, w2, dw, slots);
  k_wq<<<3134, 256, 0, stream>>>(w1, w2, dw, w1q, w2q, dwq, slots);
  k_ln<<<2048, 256, 0, stream>>>(x, lns, lnb, t1, slots);
  k_qa<<<2048, 256, 0, stream>>>(t1, bufD, slots);
  k_gemm<<<dim3(8, 256), 256, 0, stream>>>(bufD, w1q, b1, t4, 1024, slots, S_T1MN, S_W1, S_T4MN);
  k_glu<<<2048, 256, 0, stream>>>(t4, bufB, slots);
  k_qt<<<dim3(4, 8, 32), 64, 0, stream>>>(bufB, bufD, slots);
  k_conv<<<dim3(64, 32), 256, 0, stream>>>(bufD, dwq, dwb, bufB, slots);
  k_bn<<<2048, 256, 0, stream>>>(bufB, gm, bt, mu, vr, half2, slots);
  k_silu<<<2048, 256, 0, stream>>>(half2, bufB, slots);
  k_q2t<<<dim3(4, 16, 32), 64, 0, stream>>>(bufB, bufD, slots);
  k_gemm<<<dim3(4, 256), 256, 0, stream>>>(bufD, w2q, b2, half2, 512, slots, S_SIMN, S_W2, S_T18MN);
  k_final<<<2048, 256, 0, stream>>>(half2, out, slots);
}

// Round 2
// 801.646 us; speedup vs baseline: 1.0273x; 1.0273x over previous
//
#include <hip/hip_runtime.h>
#include <stdint.h>
#include <math.h>

#define INF __builtin_inff()

typedef __attribute__((ext_vector_type(4))) float f32x4;
typedef __attribute__((ext_vector_type(2))) float f32x2;
typedef __attribute__((ext_vector_type(8))) short s16x8;
typedef __attribute__((ext_vector_type(4))) short s16x4;

// ---- min/max + absmax scalar slots (order-preserving uint encoding) ----
#define S_XMN 0
#define S_XMX 1
#define S_T1MN 2
#define S_T1MX 3
#define S_T4MN 4
#define S_T4MX 5
#define S_T7MN 6
#define S_T7MX 7
#define S_CVMN 8
#define S_CVMX 9
#define S_BNMN 10
#define S_BNMX 11
#define S_SIMN 12
#define S_SIMX 13
#define S_T18MN 14
#define S_T18MX 15
#define S_W1 16
#define S_W2 17
#define S_DW 18
#define NSLOT 19

#define NTOT 16777216L   // 32*1024*512

__device__ __forceinline__ unsigned enc(float f) {
  unsigned u = __float_as_uint(f);
  return (u & 0x80000000u) ? ~u : (u | 0x80000000u);
}
__device__ __forceinline__ float dec(unsigned k) {
  return (k & 0x80000000u) ? __uint_as_float(k & 0x7FFFFFFFu) : __uint_as_float(~k);
}

struct FQ { float s, zp; };

__device__ __forceinline__ FQ fq_params(float mn_t, float mx_t) {
  float mn = fminf(mn_t, 0.0f), mx = fmaxf(mx_t, 0.0f);
  FQ p;
  p.s = fmaxf((mx - mn) / 255.0f, 1e-8f);
  p.zp = -128.0f - rintf(mn / p.s);
  return p;
}
__device__ __forceinline__ float fq_apply(float x, FQ p) {
  float q = rintf(x / p.s) + p.zp;
  q = fminf(fmaxf(q, -128.0f), 127.0f);
  return (q - p.zp) * p.s;
}
// integer-valued (q - zp) in [-255,255]
__device__ __forceinline__ float fq_qmz(float x, FQ p) {
  float q = rintf(x / p.s) + p.zp;
  q = fminf(fmaxf(q, -128.0f), 127.0f);
  return q - p.zp;
}
// double-fq: second observer sees fq1(min), fq1(max) (fq is monotone)
__device__ __forceinline__ void fq_pair(const unsigned* slots, int idx, FQ& p1, FQ& p2) {
  float mn = dec(slots[idx]), mx = dec(slots[idx + 1]);
  p1 = fq_params(mn, mx);
  float ymn = fq_apply(mn, p1), ymx = fq_apply(mx, p1);
  p2 = fq_params(ymn, ymx);
}
__device__ __forceinline__ unsigned short to_bf16(float v) {  // exact for small ints
  return (unsigned short)(__float_as_uint(v) >> 16);
}
__device__ __forceinline__ float from_bf16(unsigned short u) {
  return __uint_as_float(((unsigned)u) << 16);
}

__device__ __forceinline__ void mm_block_atomic(float mn, float mx, unsigned* smn, unsigned* smx) {
#pragma unroll
  for (int o = 32; o > 0; o >>= 1) {
    mn = fminf(mn, __shfl_down(mn, o, 64));
    mx = fmaxf(mx, __shfl_down(mx, o, 64));
  }
  __shared__ float rmn[16], rmx[16];
  int lane = threadIdx.x & 63, wid = threadIdx.x >> 6;
  int nw = blockDim.x >> 6;
  __syncthreads();
  if (lane == 0) { rmn[wid] = mn; rmx[wid] = mx; }
  __syncthreads();
  if (threadIdx.x == 0) {
    for (int i = 1; i < nw; ++i) { mn = fminf(mn, rmn[i]); mx = fmaxf(mx, rmx[i]); }
    atomicMin(smn, enc(mn));
    atomicMax(smx, enc(mx));
  }
}

// init slots + precompute bn gscale table
__global__ void k_init(unsigned* __restrict__ slots, const float* __restrict__ gm,
                       const float* __restrict__ vr, float* __restrict__ gs) {
  int i = threadIdx.x;
  if (i < NSLOT) slots[i] = (i < 16) ? ((i & 1) ? enc(-INF) : enc(INF)) : enc(0.0f);
  gs[i] = gm[i] / sqrtf(vr[i] + 1e-5f);
}

__global__ __launch_bounds__(256) void k_redmm(const float* __restrict__ x, unsigned* __restrict__ slots) {
  long i = ((long)blockIdx.x * 256 + threadIdx.x) * 4;
  const long stride = (long)2048 * 256 * 4;
  float mn = INF, mx = -INF;
  for (; i < NTOT; i += stride) {
    f32x4 v = *(const f32x4*)(x + i);
    mn = fminf(mn, fminf(fminf(v.x, v.y), fminf(v.z, v.w)));
    mx = fmaxf(mx, fmaxf(fmaxf(v.x, v.y), fmaxf(v.z, v.w)));
  }
  mm_block_atomic(mn, mx, slots + S_XMN, slots + S_XMX);
}

// blocks: [0,2048)=w1, [2048,3072)=w2, [3072,3134)=dw_w
__global__ __launch_bounds__(256) void k_wabs(const float* __restrict__ w1, const float* __restrict__ w2,
                                              const float* __restrict__ dw, unsigned* __restrict__ slots) {
  int b = blockIdx.x;
  const float* p; int slot; long base;
  if (b < 2048) { p = w1; slot = S_W1; base = (long)b * 256; }
  else if (b < 3072) { p = w2; slot = S_W2; base = (long)(b - 2048) * 256; }
  else { p = dw; slot = S_DW; base = (long)(b - 3072) * 256; }
  float v = fabsf(p[base + threadIdx.x]);
#pragma unroll
  for (int o = 32; o > 0; o >>= 1) v = fmaxf(v, __shfl_down(v, o, 64));
  __shared__ float r[4];
  int lane = threadIdx.x & 63, wid = threadIdx.x >> 6;
  if (lane == 0) r[wid] = v;
  __syncthreads();
  if (threadIdx.x == 0) {
    v = fmaxf(fmaxf(r[0], r[1]), fmaxf(r[2], r[3]));
    atomicMax(slots + slot, enc(v));
  }
}

// symmetric weight quant: integer q stored as bf16 (w1,w2) / fp32 (dw)
__global__ __launch_bounds__(256) void k_wq(const float* __restrict__ w1, const float* __restrict__ w2,
    const float* __restrict__ dw, unsigned short* __restrict__ w1q, unsigned short* __restrict__ w2q,
    float* __restrict__ dwq, const unsigned* __restrict__ slots) {
  int b = blockIdx.x;
  if (b < 2048) {
    float s = fmaxf(dec(slots[S_W1]) / 127.0f, 1e-8f);
    long i = (long)b * 256 + threadIdx.x;
    float q = fminf(fmaxf(rintf(w1[i] / s), -128.0f), 127.0f);
    w1q[i] = to_bf16(q);
  } else if (b < 3072) {
    float s = fmaxf(dec(slots[S_W2]) / 127.0f, 1e-8f);
    long i = (long)(b - 2048) * 256 + threadIdx.x;
    float q = fminf(fmaxf(rintf(w2[i] / s), -128.0f), 127.0f);
    w2q[i] = to_bf16(q);
  } else {
    float s = fmaxf(dec(slots[S_DW]) / 127.0f, 1e-8f);
    long i = (long)(b - 3072) * 256 + threadIdx.x;
    float q = fminf(fmaxf(rintf(dw[i] / s), -128.0f), 127.0f);
    dwq[i] = q;
  }
}

__device__ __forceinline__ float block_sum256(float v, float* sh) {
#pragma unroll
  for (int o = 32; o > 0; o >>= 1) v += __shfl_down(v, o, 64);
  int lane = threadIdx.x & 63, wid = threadIdx.x >> 6;
  __syncthreads();
  if (lane == 0) sh[wid] = v;
  __syncthreads();
  return sh[0] + sh[1] + sh[2] + sh[3];
}

// shared LN row computation — MUST be bitwise-identical between both passes
__device__ __forceinline__ f32x2 ln_row(const float* __restrict__ xr, int c, FQ p0,
                                        f32x2 sc, f32x2 bi, float* sh) {
  f32x2 xv = *(const f32x2*)(xr + c);
  float a0 = fq_apply(xv.x, p0), a1 = fq_apply(xv.y, p0);
  float mean = block_sum256(a0 + a1, sh) / 512.0f;
  a0 -= mean; a1 -= mean;
  float denom = block_sum256(fabsf(a0) + fabsf(a1), sh) / 512.0f + 1e-5f;
  f32x2 o;
  o.x = (a0 / denom) * sc.x + bi.x;
  o.y = (a1 / denom) * sc.y + bi.y;
  return o;
}

// pass 1: LN min/max only (no store)
__global__ __launch_bounds__(256) void k_lnmm(const float* __restrict__ x, const float* __restrict__ lns,
    const float* __restrict__ lnb, unsigned* __restrict__ slots) {
  __shared__ float sh[4];
  FQ p0 = fq_params(dec(slots[S_XMN]), dec(slots[S_XMX]));
  int c = threadIdx.x * 2;
  f32x2 sc = *(const f32x2*)(lns + c);
  f32x2 bi = *(const f32x2*)(lnb + c);
  float lmn = INF, lmx = -INF;
  for (int rr = 0; rr < 16; ++rr) {
    long row = (long)blockIdx.x * 16 + rr;
    f32x2 a = ln_row(x + row * 512, c, p0, sc, bi, sh);
    lmn = fminf(lmn, fminf(a.x, a.y));
    lmx = fmaxf(lmx, fmaxf(a.x, a.y));
  }
  mm_block_atomic(lmn, lmx, slots + S_T1MN, slots + S_T1MX);
}

// pass 2: recompute LN (bitwise-identical), double-fq -> integer bf16 A1
__global__ __launch_bounds__(256) void k_qa(const float* __restrict__ x, const float* __restrict__ lns,
    const float* __restrict__ lnb, unsigned short* __restrict__ A1, const unsigned* __restrict__ slots) {
  __shared__ float sh[4];
  FQ p0 = fq_params(dec(slots[S_XMN]), dec(slots[S_XMX]));
  FQ p1, p2; fq_pair(slots, S_T1MN, p1, p2);
  int c = threadIdx.x * 2;
  f32x2 sc = *(const f32x2*)(lns + c);
  f32x2 bi = *(const f32x2*)(lnb + c);
  for (int rr = 0; rr < 16; ++rr) {
    long row = (long)blockIdx.x * 16 + rr;
    f32x2 a = ln_row(x + row * 512, c, p0, sc, bi, sh);
    unsigned pk = (unsigned)to_bf16(fq_qmz(fq_apply(a.x, p1), p2))
                | ((unsigned)to_bf16(fq_qmz(fq_apply(a.y, p1), p2)) << 16);
    *(unsigned*)(A1 + row * 512 + c) = pk;
  }
}

// bf16-integer MFMA GEMM: A[M,512] k-major, Bm[N,512] k-major; M=32768, K=512.
__global__ __launch_bounds__(256) void k_gemm(const unsigned short* __restrict__ A,
    const unsigned short* __restrict__ Bm, const float* __restrict__ bias,
    float* __restrict__ C, int N, unsigned* __restrict__ slots, int mmIdx, int wIdx, int omIdx) {
  __shared__ __align__(16) unsigned short lA[128 * 64];
  __shared__ __align__(16) unsigned short lB[128 * 64];
  FQ p1, p2; fq_pair(slots, mmIdx, p1, p2);
  float sw = fmaxf(dec(slots[wIdx]) / 127.0f, 1e-8f);
  float sAB = p2.s * sw;
  int tid = threadIdx.x;
  int m0 = blockIdx.y * 128, n0 = blockIdx.x * 128;
  int lane = tid & 63, wid = tid >> 6;
  int wm = (wid >> 1) * 64, wn = (wid & 1) * 64;
  const f32x4 fz = {0.0f, 0.0f, 0.0f, 0.0f};
  f32x4 acc[4][4];
#pragma unroll
  for (int mi = 0; mi < 4; ++mi)
#pragma unroll
    for (int ni = 0; ni < 4; ++ni) acc[mi][ni] = fz;
  int sr = tid >> 1;
  int scu = (tid & 1) * 32;
  int swz = (sr & 7) * 8;
  const unsigned short* Ag = A + (long)(m0 + sr) * 512 + scu;
  const unsigned short* Bg = Bm + (long)(n0 + sr) * 512 + scu;
  int fr = lane & 15;
  int fc = (lane >> 4) * 8;
  for (int kt = 0; kt < 8; ++kt) {
    s16x8 ra[4], rb[4];
#pragma unroll
    for (int j = 0; j < 4; ++j) {
      ra[j] = *(const s16x8*)(Ag + kt * 64 + j * 8);
      rb[j] = *(const s16x8*)(Bg + kt * 64 + j * 8);
    }
    __syncthreads();
#pragma unroll
    for (int j = 0; j < 4; ++j) {
      *(s16x8*)&lA[sr * 64 + ((scu + j * 8) ^ swz)] = ra[j];
      *(s16x8*)&lB[sr * 64 + ((scu + j * 8) ^ swz)] = rb[j];
    }
    __syncthreads();
#pragma unroll
    for (int ks = 0; ks < 2; ++ks) {
      s16x8 af[4], bfv[4];
#pragma unroll
      for (int mi = 0; mi < 4; ++mi) {
        int r = wm + mi * 16 + fr;
        af[mi] = *(const s16x8*)&lA[r * 64 + ((ks * 32 + fc) ^ ((r & 7) * 8))];
      }
#pragma unroll
      for (int ni = 0; ni < 4; ++ni) {
        int r = wn + ni * 16 + fr;
        bfv[ni] = *(const s16x8*)&lB[r * 64 + ((ks * 32 + fc) ^ ((r & 7) * 8))];
      }
#pragma unroll
      for (int mi = 0; mi < 4; ++mi)
#pragma unroll
        for (int ni = 0; ni < 4; ++ni)
          acc[mi][ni] = __builtin_amdgcn_mfma_f32_16x16x32_bf16(af[mi], bfv[ni], acc[mi][ni], 0, 0, 0);
    }
  }
  float lmn = INF, lmx = -INF;
  int rb0 = m0 + wm + ((lane >> 4) << 2);
  int cb0 = n0 + wn + (lane & 15);
#pragma unroll
  for (int mi = 0; mi < 4; ++mi) {
#pragma unroll
    for (int ni = 0; ni < 4; ++ni) {
      int col = cb0 + ni * 16;
      float bv = bias[col];
#pragma unroll
      for (int r = 0; r < 4; ++r) {
        int rowi = rb0 + mi * 16 + r;
        float v = sAB * acc[mi][ni][r] + bv;
        C[(long)rowi * N + col] = v;
        lmn = fminf(lmn, v); lmx = fmaxf(lmx, v);
      }
    }
  }
  mm_block_atomic(lmn, lmx, slots + omIdx, slots + omIdx + 1);
}

// GLU: a,g = split(fq2(t4)); t7 = a*sigmoid(g); mm(t7)
__global__ __launch_bounds__(256) void k_glu(const float* __restrict__ t4, float* __restrict__ t7,
                                             unsigned* __restrict__ slots) {
  FQ p1, p2; fq_pair(slots, S_T4MN, p1, p2);
  long i = ((long)blockIdx.x * 256 + threadIdx.x) * 4;
  const long stride = (long)2048 * 256 * 4;
  float lmn = INF, lmx = -INF;
  for (; i < NTOT; i += stride) {
    long r = i >> 9;
    int c = (int)(i & 511);
    const float* pa = t4 + r * 1024 + c;
    f32x4 av = *(const f32x4*)pa;
    f32x4 gv = *(const f32x4*)(pa + 512);
    f32x4 o;
#pragma unroll
    for (int j = 0; j < 4; ++j) {
      float a = fq_apply(fq_apply(av[j], p1), p2);
      float g = fq_apply(fq_apply(gv[j], p1), p2);
      float y = a * (1.0f / (1.0f + expf(-g)));
      o[j] = y;
      lmn = fminf(lmn, y); lmx = fmaxf(lmx, y);
    }
    *(f32x4*)(t7 + i) = o;
  }
  mm_block_atomic(lmn, lmx, slots + S_T7MN, slots + S_T7MX);
}

// depthwise conv over time, [B,T,F] layout, fused quantize of t7; per-thread channel column.
// grid (T/32, F/256, B), block 256. Integer dot (<=1.0M < 2^24, exact) * (s*sdw) + bias.
__global__ __launch_bounds__(256) void k_conv(const float* __restrict__ t7,
    const float* __restrict__ dwq, const float* __restrict__ dwb,
    float* __restrict__ out, unsigned* __restrict__ slots) {
  FQ p1, p2; fq_pair(slots, S_T7MN, p1, p2);
  float sdw = fmaxf(dec(slots[S_DW]) / 127.0f, 1e-8f);
  float scv = p2.s * sdw;
  int t0 = blockIdx.x * 32;
  int f = blockIdx.y * 256 + threadIdx.x;
  int b = blockIdx.z;
  const float* base = t7 + (long)b * 1024 * 512 + f;
  float col[62];
#pragma unroll
  for (int r = 0; r < 62; ++r) {
    int t = t0 - 15 + r;
    float q = 0.0f;   // zero-pad = integer 0 (pad applied post-quant in reference)
    if ((unsigned)t < 1024u) q = fq_qmz(fq_apply(base[(long)t * 512], p1), p2);
    col[r] = q;
  }
  float w31[31];
#pragma unroll
  for (int k = 0; k < 31; ++k) w31[k] = dwq[f * 31 + k];
  float bias = dwb[f];
  float* orow = out + ((long)b * 1024 + t0) * 512 + f;
  float lmn = INF, lmx = -INF;
#pragma unroll
  for (int j = 0; j < 32; ++j) {
    float acc = 0.0f;
#pragma unroll
    for (int k = 0; k < 31; ++k) acc += col[j + k] * w31[k];
    float v = scv * acc + bias;
    lmn = fminf(lmn, v); lmx = fmaxf(lmx, v);
    orow[(long)j * 512] = v;
  }
  mm_block_atomic(lmn, lmx, slots + S_CVMN, slots + S_CVMX);
}

// bn recompute chain from convout (shared by the three downstream passes)
__device__ __forceinline__ float bn_val(float v, FQ c1, FQ c2, float gsv, float muv, float btv) {
  float y = fq_apply(fq_apply(v, c1), c2);
  return (y - muv) * gsv + btv;
}

// pass: mm of bn output (no store)
__global__ __launch_bounds__(256) void k_bnmm(const float* __restrict__ conv,
    const float* __restrict__ gs, const float* __restrict__ mu, const float* __restrict__ bt,
    unsigned* __restrict__ slots) {
  FQ c1, c2; fq_pair(slots, S_CVMN, c1, c2);
  long i = ((long)blockIdx.x * 256 + threadIdx.x) * 4;
  const long stride = (long)2048 * 256 * 4;
  float lmn = INF, lmx = -INF;
  for (; i < NTOT; i += stride) {
    int f0 = (int)(i & 511);
    f32x4 v = *(const f32x4*)(conv + i);
    f32x4 g4 = *(const f32x4*)(gs + f0);
    f32x4 m4 = *(const f32x4*)(mu + f0);
    f32x4 b4 = *(const f32x4*)(bt + f0);
#pragma unroll
    for (int j = 0; j < 4; ++j) {
      float r2 = bn_val(v[j], c1, c2, g4[j], m4[j], b4[j]);
      lmn = fminf(lmn, r2); lmx = fmaxf(lmx, r2);
    }
  }
  mm_block_atomic(lmn, lmx, slots + S_BNMN, slots + S_BNMX);
}

// pass: recompute bn, fq2, silu; mm of silu output (no store)
__global__ __launch_bounds__(256) void k_silumm(const float* __restrict__ conv,
    const float* __restrict__ gs, const float* __restrict__ mu, const float* __restrict__ bt,
    unsigned* __restrict__ slots) {
  FQ c1, c2; fq_pair(slots, S_CVMN, c1, c2);
  FQ b1q, b2q; fq_pair(slots, S_BNMN, b1q, b2q);
  long i = ((long)blockIdx.x * 256 + threadIdx.x) * 4;
  const long stride = (long)2048 * 256 * 4;
  float lmn = INF, lmx = -INF;
  for (; i < NTOT; i += stride) {
    int f0 = (int)(i & 511);
    f32x4 v = *(const f32x4*)(conv + i);
    f32x4 g4 = *(const f32x4*)(gs + f0);
    f32x4 m4 = *(const f32x4*)(mu + f0);
    f32x4 b4 = *(const f32x4*)(bt + f0);
#pragma unroll
    for (int j = 0; j < 4; ++j) {
      float z = fq_apply(fq_apply(bn_val(v[j], c1, c2, g4[j], m4[j], b4[j]), b1q), b2q);
      float si = z * (1.0f / (1.0f + expf(-z)));
      lmn = fminf(lmn, si); lmx = fmaxf(lmx, si);
    }
  }
  mm_block_atomic(lmn, lmx, slots + S_SIMN, slots + S_SIMX);
}

// pass: recompute bn+silu, double-fq -> integer bf16 A2 (no transpose: already [B,T,F])
__global__ __launch_bounds__(256) void k_q2(const float* __restrict__ conv,
    const float* __restrict__ gs, const float* __restrict__ mu, const float* __restrict__ bt,
    unsigned short* __restrict__ A2, const unsigned* __restrict__ slots) {
  FQ c1, c2; fq_pair(slots, S_CVMN, c1, c2);
  FQ b1q, b2q; fq_pair(slots, S_BNMN, b1q, b2q);
  FQ s1, s2; fq_pair(slots, S_SIMN, s1, s2);
  long i = ((long)blockIdx.x * 256 + threadIdx.x) * 4;
  const long stride = (long)2048 * 256 * 4;
  for (; i < NTOT; i += stride) {
    int f0 = (int)(i & 511);
    f32x4 v = *(const f32x4*)(conv + i);
    f32x4 g4 = *(const f32x4*)(gs + f0);
    f32x4 m4 = *(const f32x4*)(mu + f0);
    f32x4 b4 = *(const f32x4*)(bt + f0);
    s16x4 o;
#pragma unroll
    for (int j = 0; j < 4; ++j) {
      float z = fq_apply(fq_apply(bn_val(v[j], c1, c2, g4[j], m4[j], b4[j]), b1q), b2q);
      float si = z * (1.0f / (1.0f + expf(-z)));
      o[j] = (short)to_bf16(fq_qmz(fq_apply(si, s1), s2));
    }
    *(s16x4*)(A2 + i) = o;
  }
}

__global__ __launch_bounds__(256) void k_final(const float* __restrict__ t18, float* __restrict__ out,
                                               const unsigned* __restrict__ slots) {
  FQ p = fq_params(dec(slots[S_T18MN]), dec(slots[S_T18MX]));
  long i = ((long)blockIdx.x * 256 + threadIdx.x) * 4;
  const long stride = (long)2048 * 256 * 4;
  for (; i < NTOT; i += stride) {
    f32x4 v = *(const f32x4*)(t18 + i);
    f32x4 o;
#pragma unroll
    for (int j = 0; j < 4; ++j) o[j] = fq_apply(v[j], p);
    *(f32x4*)(out + i) = o;
  }
}

extern "C" void kernel_launch(void* const* d_in, const int* in_sizes, int n_in,
                              void* d_out, int out_size, void* d_ws, size_t ws_size,
                              hipStream_t stream) {
  const float* x   = (const float*)d_in[0];
  const float* lns = (const float*)d_in[1];
  const float* lnb = (const float*)d_in[2];
  const float* w1  = (const float*)d_in[3];
  const float* b1  = (const float*)d_in[4];
  const float* dw  = (const float*)d_in[5];
  const float* dwb = (const float*)d_in[6];
  const float* gm  = (const float*)d_in[7];
  const float* bt  = (const float*)d_in[8];
  const float* mu  = (const float*)d_in[9];
  const float* vr  = (const float*)d_in[10];
  const float* w2  = (const float*)d_in[11];
  const float* b2  = (const float*)d_in[12];
  float* out = (float*)d_out;
  char* ws = (char*)d_ws;

  // workspace (aliased lifetimes):
  //  buf0 [0,134MB):   t4 (gemm1 out) -> convout (first 67MB)
  //  bufB [134,201MB): t7 (glu out)   -> t18 (gemm2 out)
  //  bufD [201,234.5): A1 -> A2 (bf16 int, 33.5MB)
  //  then w1q(1MB), w2q(0.5MB), dwq(63.5KB f32), gs(2KB), slots
  const size_t OFF_B = 134217728;
  const size_t OFF_D = OFF_B + 67108864;
  const size_t OFF_W = OFF_D + 33554432;
  const size_t NEED = OFF_W + 1048576 + 524288 + 63488 + 2048 + 256;
  if (ws_size < NEED) return;

  float* buf0 = (float*)ws;
  float* bufB = (float*)(ws + OFF_B);
  unsigned short* bufD = (unsigned short*)(ws + OFF_D);
  unsigned short* w1q = (unsigned short*)(ws + OFF_W);
  unsigned short* w2q = (unsigned short*)(ws + OFF_W + 1048576);
  float* dwq = (float*)(ws + OFF_W + 1048576 + 524288);
  float* gs  = (float*)(ws + OFF_W + 1048576 + 524288 + 63488);
  unsigned* slots = (unsigned*)(ws + OFF_W + 1048576 + 524288 + 63488 + 2048);

  k_init<<<1, 512, 0, stream>>>(slots, gm, vr, gs);
  k_redmm<<<2048, 256, 0, stream>>>(x, slots);
  k_wabs<<<3134, 256, 0, stream>>>(w1, w2, dw, slots);
  k_wq<<<3134, 256, 0, stream>>>(w1, w2, dw, w1q, w2q, dwq, slots);
  k_lnmm<<<2048, 256, 0, stream>>>(x, lns, lnb, slots);
  k_qa<<<2048, 256, 0, stream>>>(x, lns, lnb, bufD, slots);
  k_gemm<<<dim3(8, 256), 256, 0, stream>>>(bufD, w1q, b1, buf0, 1024, slots, S_T1MN, S_W1, S_T4MN);
  k_glu<<<2048, 256, 0, stream>>>(buf0, bufB, slots);
  k_conv<<<dim3(32, 2, 32), 256, 0, stream>>>(bufB, dwq, dwb, buf0, slots);
  k_bnmm<<<2048, 256, 0, stream>>>(buf0, gs, mu, bt, slots);
  k_silumm<<<2048, 256, 0, stream>>>(buf0, gs, mu, bt, slots);
  k_q2<<<2048, 256, 0, stream>>>(buf0, gs, mu, bt, bufD, slots);
  k_gemm<<<dim3(4, 256), 256, 0, stream>>>(bufD, w2q, b2, bufB, 512, slots, S_SIMN, S_W2, S_T18MN);
  k_final<<<2048, 256, 0, stream>>>(bufB, out, slots);
}

// Round 3
// 748.679 us; speedup vs baseline: 1.1000x; 1.0707x over previous
//
#include <hip/hip_runtime.h>
#include <stdint.h>
#include <math.h>

#define INF __builtin_inff()

typedef __attribute__((ext_vector_type(4))) float f32x4;
typedef __attribute__((ext_vector_type(8))) short s16x8;
typedef __attribute__((ext_vector_type(4))) short s16x4;
typedef __attribute__((ext_vector_type(4))) char c8x4;

// ---- min/max + absmax scalar slots (order-preserving uint encoding) ----
#define S_XMN 0
#define S_XMX 1
#define S_T1MN 2
#define S_T1MX 3
#define S_T4MN 4
#define S_T4MX 5
#define S_T7MN 6
#define S_T7MX 7
#define S_CVMN 8
#define S_CVMX 9
#define S_BNMN 10
#define S_BNMX 11
#define S_SIMN 12
#define S_SIMX 13
#define S_T18MN 14
#define S_T18MX 15
#define S_W1 16
#define S_W2 17
#define S_DW 18
#define NSLOT 19

#define NTOT 16777216L   // 32*1024*512

__device__ __forceinline__ unsigned enc(float f) {
  unsigned u = __float_as_uint(f);
  return (u & 0x80000000u) ? ~u : (u | 0x80000000u);
}
__device__ __forceinline__ float dec(unsigned k) {
  return (k & 0x80000000u) ? __uint_as_float(k & 0x7FFFFFFFu) : __uint_as_float(~k);
}

struct FQ { float s, zp; };

__device__ __forceinline__ FQ fq_params(float mn_t, float mx_t) {
  float mn = fminf(mn_t, 0.0f), mx = fmaxf(mx_t, 0.0f);
  FQ p;
  p.s = fmaxf((mx - mn) / 255.0f, 1e-8f);
  p.zp = -128.0f - rintf(mn / p.s);
  return p;
}
__device__ __forceinline__ float fq_apply(float x, FQ p) {
  float q = rintf(x / p.s) + p.zp;
  q = fminf(fmaxf(q, -128.0f), 127.0f);
  return (q - p.zp) * p.s;
}
// integer-valued (q - zp) in [-255,255]
__device__ __forceinline__ float fq_qmz(float x, FQ p) {
  float q = rintf(x / p.s) + p.zp;
  q = fminf(fmaxf(q, -128.0f), 127.0f);
  return q - p.zp;
}
// quantize to LUT index in [0,255]  (ONE division)
__device__ __forceinline__ int qidx(float x, FQ p) {
  float q = rintf(x / p.s) + p.zp;
  q = fminf(fmaxf(q, -128.0f), 127.0f);
  return (int)q + 128;
}
// double-fq: second observer sees fq1(min), fq1(max) (fq is monotone)
__device__ __forceinline__ void fq_pair(const unsigned* slots, int idx, FQ& p1, FQ& p2) {
  float mn = dec(slots[idx]), mx = dec(slots[idx + 1]);
  p1 = fq_params(mn, mx);
  float ymn = fq_apply(mn, p1), ymx = fq_apply(mx, p1);
  p2 = fq_params(ymn, ymx);
}
__device__ __forceinline__ unsigned short to_bf16(float v) {  // exact for small ints
  return (unsigned short)(__float_as_uint(v) >> 16);
}

__device__ __forceinline__ void mm_block_atomic(float mn, float mx, unsigned* smn, unsigned* smx) {
#pragma unroll
  for (int o = 32; o > 0; o >>= 1) {
    mn = fminf(mn, __shfl_down(mn, o, 64));
    mx = fmaxf(mx, __shfl_down(mx, o, 64));
  }
  __shared__ float rmn[16], rmx[16];
  int lane = threadIdx.x & 63, wid = threadIdx.x >> 6;
  int nw = blockDim.x >> 6;
  __syncthreads();
  if (lane == 0) { rmn[wid] = mn; rmx[wid] = mx; }
  __syncthreads();
  if (threadIdx.x == 0) {
    for (int i = 1; i < nw; ++i) { mn = fminf(mn, rmn[i]); mx = fmaxf(mx, rmx[i]); }
    atomicMin(smn, enc(mn));
    atomicMax(smx, enc(mx));
  }
}

__device__ __forceinline__ float wave_sum(float v) {
#pragma unroll
  for (int o = 1; o < 64; o <<= 1) v += __shfl_xor(v, o, 64);
  return v;
}

// init slots + precompute bn gscale table
__global__ void k_init(unsigned* __restrict__ slots, const float* __restrict__ gm,
                       const float* __restrict__ vr, float* __restrict__ gs) {
  int i = threadIdx.x;
  if (i < NSLOT) slots[i] = (i < 16) ? ((i & 1) ? enc(-INF) : enc(INF)) : enc(0.0f);
  gs[i] = gm[i] / sqrtf(vr[i] + 1e-5f);
}

__global__ __launch_bounds__(256) void k_redmm(const float* __restrict__ x, unsigned* __restrict__ slots) {
  long i = ((long)blockIdx.x * 256 + threadIdx.x) * 4;
  const long stride = (long)2048 * 256 * 4;
  float mn = INF, mx = -INF;
  for (; i < NTOT; i += stride) {
    f32x4 v = *(const f32x4*)(x + i);
    mn = fminf(mn, fminf(fminf(v.x, v.y), fminf(v.z, v.w)));
    mx = fmaxf(mx, fmaxf(fmaxf(v.x, v.y), fmaxf(v.z, v.w)));
  }
  mm_block_atomic(mn, mx, slots + S_XMN, slots + S_XMX);
}

// blocks: [0,2048)=w1, [2048,3072)=w2, [3072,3134)=dw_w
__global__ __launch_bounds__(256) void k_wabs(const float* __restrict__ w1, const float* __restrict__ w2,
                                              const float* __restrict__ dw, unsigned* __restrict__ slots) {
  int b = blockIdx.x;
  const float* p; int slot; long base;
  if (b < 2048) { p = w1; slot = S_W1; base = (long)b * 256; }
  else if (b < 3072) { p = w2; slot = S_W2; base = (long)(b - 2048) * 256; }
  else { p = dw; slot = S_DW; base = (long)(b - 3072) * 256; }
  float v = fabsf(p[base + threadIdx.x]);
#pragma unroll
  for (int o = 32; o > 0; o >>= 1) v = fmaxf(v, __shfl_down(v, o, 64));
  __shared__ float r[4];
  int lane = threadIdx.x & 63, wid = threadIdx.x >> 6;
  if (lane == 0) r[wid] = v;
  __syncthreads();
  if (threadIdx.x == 0) {
    v = fmaxf(fmaxf(r[0], r[1]), fmaxf(r[2], r[3]));
    atomicMax(slots + slot, enc(v));
  }
}

// symmetric weight quant: integer q stored as bf16 (w1,w2) / fp32 (dw)
__global__ __launch_bounds__(256) void k_wq(const float* __restrict__ w1, const float* __restrict__ w2,
    const float* __restrict__ dw, unsigned short* __restrict__ w1q, unsigned short* __restrict__ w2q,
    float* __restrict__ dwq, const unsigned* __restrict__ slots) {
  int b = blockIdx.x;
  if (b < 2048) {
    float s = fmaxf(dec(slots[S_W1]) / 127.0f, 1e-8f);
    long i = (long)b * 256 + threadIdx.x;
    float q = fminf(fmaxf(rintf(w1[i] / s), -128.0f), 127.0f);
    w1q[i] = to_bf16(q);
  } else if (b < 3072) {
    float s = fmaxf(dec(slots[S_W2]) / 127.0f, 1e-8f);
    long i = (long)(b - 2048) * 256 + threadIdx.x;
    float q = fminf(fmaxf(rintf(w2[i] / s), -128.0f), 127.0f);
    w2q[i] = to_bf16(q);
  } else {
    float s = fmaxf(dec(slots[S_DW]) / 127.0f, 1e-8f);
    long i = (long)(b - 3072) * 256 + threadIdx.x;
    float q = fminf(fmaxf(rintf(dw[i] / s), -128.0f), 127.0f);
    dwq[i] = q;
  }
}

// wave-per-row L1-LN. Lane owns cols [l*4,l*4+4) and [256+l*4, ...). Returns 8 outputs.
// MUST be bitwise-identical between k_lnmm and k_qa.
__device__ __forceinline__ void ln_row_wave(const float* __restrict__ xr, int lane, FQ p0,
    const f32x4& sc0, const f32x4& sc1, const f32x4& bi0, const f32x4& bi1,
    f32x4& o0, f32x4& o1) {
  f32x4 v0 = *(const f32x4*)(xr + lane * 4);
  f32x4 v1 = *(const f32x4*)(xr + 256 + lane * 4);
  float a[8];
#pragma unroll
  for (int j = 0; j < 4; ++j) { a[j] = fq_apply(v0[j], p0); a[4 + j] = fq_apply(v1[j], p0); }
  float s = a[0] + a[1] + a[2] + a[3] + a[4] + a[5] + a[6] + a[7];
  float mean = wave_sum(s) / 512.0f;
#pragma unroll
  for (int j = 0; j < 8; ++j) a[j] -= mean;
  float l1 = fabsf(a[0]) + fabsf(a[1]) + fabsf(a[2]) + fabsf(a[3])
           + fabsf(a[4]) + fabsf(a[5]) + fabsf(a[6]) + fabsf(a[7]);
  float denom = wave_sum(l1) / 512.0f + 1e-5f;
#pragma unroll
  for (int j = 0; j < 4; ++j) {
    o0[j] = (a[j] / denom) * sc0[j] + bi0[j];
    o1[j] = (a[4 + j] / denom) * sc1[j] + bi1[j];
  }
}

// pass 1: LN min/max only (no store)
__global__ __launch_bounds__(256) void k_lnmm(const float* __restrict__ x, const float* __restrict__ lns,
    const float* __restrict__ lnb, unsigned* __restrict__ slots) {
  FQ p0 = fq_params(dec(slots[S_XMN]), dec(slots[S_XMX]));
  int lane = threadIdx.x & 63, wv = threadIdx.x >> 6;
  long gw = (long)blockIdx.x * 4 + wv;   // 8192 waves, 4 rows each
  f32x4 sc0 = *(const f32x4*)(lns + lane * 4);
  f32x4 sc1 = *(const f32x4*)(lns + 256 + lane * 4);
  f32x4 bi0 = *(const f32x4*)(lnb + lane * 4);
  f32x4 bi1 = *(const f32x4*)(lnb + 256 + lane * 4);
  float lmn = INF, lmx = -INF;
  for (int r = 0; r < 4; ++r) {
    long row = gw + (long)r * 8192;
    f32x4 o0, o1;
    ln_row_wave(x + row * 512, lane, p0, sc0, sc1, bi0, bi1, o0, o1);
#pragma unroll
    for (int j = 0; j < 4; ++j) {
      lmn = fminf(lmn, fminf(o0[j], o1[j]));
      lmx = fmaxf(lmx, fmaxf(o0[j], o1[j]));
    }
  }
  mm_block_atomic(lmn, lmx, slots + S_T1MN, slots + S_T1MX);
}

// pass 2: recompute LN (bitwise-identical), double-fq via LUT -> integer bf16 A1
__global__ __launch_bounds__(256) void k_qa(const float* __restrict__ x, const float* __restrict__ lns,
    const float* __restrict__ lnb, unsigned short* __restrict__ A1, const unsigned* __restrict__ slots) {
  __shared__ unsigned short lut[256];
  FQ p0 = fq_params(dec(slots[S_XMN]), dec(slots[S_XMX]));
  FQ p1, p2; fq_pair(slots, S_T1MN, p1, p2);
  {
    int i = threadIdx.x;
    float y1 = ((float)(i - 128) - p1.zp) * p1.s;
    lut[i] = to_bf16(fq_qmz(y1, p2));
  }
  __syncthreads();
  int lane = threadIdx.x & 63, wv = threadIdx.x >> 6;
  long gw = (long)blockIdx.x * 4 + wv;
  f32x4 sc0 = *(const f32x4*)(lns + lane * 4);
  f32x4 sc1 = *(const f32x4*)(lns + 256 + lane * 4);
  f32x4 bi0 = *(const f32x4*)(lnb + lane * 4);
  f32x4 bi1 = *(const f32x4*)(lnb + 256 + lane * 4);
  for (int r = 0; r < 4; ++r) {
    long row = gw + (long)r * 8192;
    f32x4 o0, o1;
    ln_row_wave(x + row * 512, lane, p0, sc0, sc1, bi0, bi1, o0, o1);
    s16x4 q0, q1;
#pragma unroll
    for (int j = 0; j < 4; ++j) {
      q0[j] = (short)lut[qidx(o0[j], p1)];
      q1[j] = (short)lut[qidx(o1[j], p1)];
    }
    *(s16x4*)(A1 + row * 512 + lane * 4) = q0;
    *(s16x4*)(A1 + row * 512 + 256 + lane * 4) = q1;
  }
}

// bf16-integer MFMA GEMM: A[M,512] k-major, Bm[N,512] k-major; M=32768, K=512.
__global__ __launch_bounds__(256) void k_gemm(const unsigned short* __restrict__ A,
    const unsigned short* __restrict__ Bm, const float* __restrict__ bias,
    float* __restrict__ C, int N, unsigned* __restrict__ slots, int mmIdx, int wIdx, int omIdx) {
  __shared__ __align__(16) unsigned short lA[128 * 64];
  __shared__ __align__(16) unsigned short lB[128 * 64];
  FQ p1, p2; fq_pair(slots, mmIdx, p1, p2);
  float sw = fmaxf(dec(slots[wIdx]) / 127.0f, 1e-8f);
  float sAB = p2.s * sw;
  int tid = threadIdx.x;
  int m0 = blockIdx.y * 128, n0 = blockIdx.x * 128;
  int lane = tid & 63, wid = tid >> 6;
  int wm = (wid >> 1) * 64, wn = (wid & 1) * 64;
  const f32x4 fz = {0.0f, 0.0f, 0.0f, 0.0f};
  f32x4 acc[4][4];
#pragma unroll
  for (int mi = 0; mi < 4; ++mi)
#pragma unroll
    for (int ni = 0; ni < 4; ++ni) acc[mi][ni] = fz;
  int sr = tid >> 1;
  int scu = (tid & 1) * 32;
  int swz = (sr & 7) * 8;
  const unsigned short* Ag = A + (long)(m0 + sr) * 512 + scu;
  const unsigned short* Bg = Bm + (long)(n0 + sr) * 512 + scu;
  int fr = lane & 15;
  int fc = (lane >> 4) * 8;
  for (int kt = 0; kt < 8; ++kt) {
    s16x8 ra[4], rb[4];
#pragma unroll
    for (int j = 0; j < 4; ++j) {
      ra[j] = *(const s16x8*)(Ag + kt * 64 + j * 8);
      rb[j] = *(const s16x8*)(Bg + kt * 64 + j * 8);
    }
    __syncthreads();
#pragma unroll
    for (int j = 0; j < 4; ++j) {
      *(s16x8*)&lA[sr * 64 + ((scu + j * 8) ^ swz)] = ra[j];
      *(s16x8*)&lB[sr * 64 + ((scu + j * 8) ^ swz)] = rb[j];
    }
    __syncthreads();
#pragma unroll
    for (int ks = 0; ks < 2; ++ks) {
      s16x8 af[4], bfv[4];
#pragma unroll
      for (int mi = 0; mi < 4; ++mi) {
        int r = wm + mi * 16 + fr;
        af[mi] = *(const s16x8*)&lA[r * 64 + ((ks * 32 + fc) ^ ((r & 7) * 8))];
      }
#pragma unroll
      for (int ni = 0; ni < 4; ++ni) {
        int r = wn + ni * 16 + fr;
        bfv[ni] = *(const s16x8*)&lB[r * 64 + ((ks * 32 + fc) ^ ((r & 7) * 8))];
      }
#pragma unroll
      for (int mi = 0; mi < 4; ++mi)
#pragma unroll
        for (int ni = 0; ni < 4; ++ni)
          acc[mi][ni] = __builtin_amdgcn_mfma_f32_16x16x32_bf16(af[mi], bfv[ni], acc[mi][ni], 0, 0, 0);
    }
  }
  float lmn = INF, lmx = -INF;
  int rb0 = m0 + wm + ((lane >> 4) << 2);
  int cb0 = n0 + wn + (lane & 15);
#pragma unroll
  for (int mi = 0; mi < 4; ++mi) {
#pragma unroll
    for (int ni = 0; ni < 4; ++ni) {
      int col = cb0 + ni * 16;
      float bv = bias[col];
#pragma unroll
      for (int r = 0; r < 4; ++r) {
        int rowi = rb0 + mi * 16 + r;
        float v = sAB * acc[mi][ni][r] + bv;
        C[(long)rowi * N + col] = v;
        lmn = fminf(lmn, v); lmx = fmaxf(lmx, v);
      }
    }
  }
  mm_block_atomic(lmn, lmx, slots + omIdx, slots + omIdx + 1);
}

// GLU: a,g = split(fq2(t4) via LUT); t7 = a*sigmoid(g); mm(t7)
__global__ __launch_bounds__(256) void k_glu(const float* __restrict__ t4, float* __restrict__ t7,
                                             unsigned* __restrict__ slots) {
  __shared__ float lut[256];
  FQ p1, p2; fq_pair(slots, S_T4MN, p1, p2);
  {
    int i = threadIdx.x;
    float y1 = ((float)(i - 128) - p1.zp) * p1.s;
    lut[i] = fq_apply(y1, p2);
  }
  __syncthreads();
  long i = ((long)blockIdx.x * 256 + threadIdx.x) * 4;
  const long stride = (long)2048 * 256 * 4;
  float lmn = INF, lmx = -INF;
  for (; i < NTOT; i += stride) {
    long r = i >> 9;
    int c = (int)(i & 511);
    const float* pa = t4 + r * 1024 + c;
    f32x4 av = *(const f32x4*)pa;
    f32x4 gv = *(const f32x4*)(pa + 512);
    f32x4 o;
#pragma unroll
    for (int j = 0; j < 4; ++j) {
      float a = lut[qidx(av[j], p1)];
      float g = lut[qidx(gv[j], p1)];
      float y = a * (1.0f / (1.0f + expf(-g)));
      o[j] = y;
      lmn = fminf(lmn, y); lmx = fmaxf(lmx, y);
    }
    *(f32x4*)(t7 + i) = o;
  }
  mm_block_atomic(lmn, lmx, slots + S_T7MN, slots + S_T7MX);
}

// quantize t7 -> int8 code q2 (1 div + LUT)
__global__ __launch_bounds__(256) void k_qt7(const float* __restrict__ t7, signed char* __restrict__ q7,
                                             const unsigned* __restrict__ slots) {
  __shared__ signed char lutq[256];
  FQ p1, p2; fq_pair(slots, S_T7MN, p1, p2);
  {
    int i = threadIdx.x;
    float y1 = ((float)(i - 128) - p1.zp) * p1.s;
    float q = fminf(fmaxf(rintf(y1 / p2.s) + p2.zp, -128.0f), 127.0f);
    lutq[i] = (signed char)(int)q;
  }
  __syncthreads();
  long i = ((long)blockIdx.x * 256 + threadIdx.x) * 4;
  const long stride = (long)2048 * 256 * 4;
  for (; i < NTOT; i += stride) {
    f32x4 v = *(const f32x4*)(t7 + i);
    c8x4 o;
#pragma unroll
    for (int j = 0; j < 4; ++j) o[j] = lutq[qidx(v[j], p1)];
    *(c8x4*)(q7 + i) = o;
  }
}

// depthwise conv over time, [B,T,F] layout, int8-code input; per-thread channel column.
// grid (T/32, F/256, B), block 256. Integer dot (<=1.0M < 2^24, exact) * (s2*sdw) + bias.
__global__ __launch_bounds__(256) void k_conv(const signed char* __restrict__ q7,
    const float* __restrict__ dwq, const float* __restrict__ dwb,
    float* __restrict__ out, unsigned* __restrict__ slots) {
  FQ p1, p2; fq_pair(slots, S_T7MN, p1, p2);
  float sdw = fmaxf(dec(slots[S_DW]) / 127.0f, 1e-8f);
  float scv = p2.s * sdw;
  float zp2 = p2.zp;
  int t0 = blockIdx.x * 32;
  int f = blockIdx.y * 256 + threadIdx.x;
  int b = blockIdx.z;
  const signed char* base = q7 + (long)b * 1024 * 512 + f;
  float col[62];
#pragma unroll
  for (int r = 0; r < 62; ++r) {
    int t = t0 - 15 + r;
    float q = 0.0f;   // zero-pad (pad applied post-quant in reference)
    if ((unsigned)t < 1024u) q = (float)(int)base[(long)t * 512] - zp2;
    col[r] = q;
  }
  float w31[31];
#pragma unroll
  for (int k = 0; k < 31; ++k) w31[k] = dwq[f * 31 + k];
  float bias = dwb[f];
  float* orow = out + ((long)b * 1024 + t0) * 512 + f;
  float lmn = INF, lmx = -INF;
#pragma unroll
  for (int j = 0; j < 32; ++j) {
    float acc = 0.0f;
#pragma unroll
    for (int k = 0; k < 31; ++k) acc += col[j + k] * w31[k];
    float v = scv * acc + bias;
    lmn = fminf(lmn, v); lmx = fmaxf(lmx, v);
    orow[(long)j * 512] = v;
  }
  mm_block_atomic(lmn, lmx, slots + S_CVMN, slots + S_CVMX);
}

// fused: quantize conv-out -> int8 code (1 div + LUT), AND bn min/max from the code
__global__ __launch_bounds__(256) void k_qcv_bnmm(const float* __restrict__ conv,
    signed char* __restrict__ qcv, const float* __restrict__ gs, const float* __restrict__ mu,
    const float* __restrict__ bt, unsigned* __restrict__ slots) {
  __shared__ signed char lutq[256];
  FQ p1, p2; fq_pair(slots, S_CVMN, p1, p2);
  {
    int i = threadIdx.x;
    float y1 = ((float)(i - 128) - p1.zp) * p1.s;
    float q = fminf(fmaxf(rintf(y1 / p2.s) + p2.zp, -128.0f), 127.0f);
    lutq[i] = (signed char)(int)q;
  }
  __syncthreads();
  float s2 = p2.s, zp2 = p2.zp;
  long i = ((long)blockIdx.x * 256 + threadIdx.x) * 4;
  const long stride = (long)2048 * 256 * 4;
  float lmn = INF, lmx = -INF;
  for (; i < NTOT; i += stride) {
    int f0 = (int)(i & 511);
    f32x4 v = *(const f32x4*)(conv + i);
    f32x4 g4 = *(const f32x4*)(gs + f0);
    f32x4 m4 = *(const f32x4*)(mu + f0);
    f32x4 b4 = *(const f32x4*)(bt + f0);
    c8x4 o;
#pragma unroll
    for (int j = 0; j < 4; ++j) {
      signed char qc = lutq[qidx(v[j], p1)];
      o[j] = qc;
      float y2 = ((float)(int)qc - zp2) * s2;
      float z = (y2 - m4[j]) * g4[j] + b4[j];
      lmn = fminf(lmn, z); lmx = fmaxf(lmx, z);
    }
    *(c8x4*)(qcv + i) = o;
  }
  mm_block_atomic(lmn, lmx, slots + S_BNMN, slots + S_BNMX);
}

// silu min/max: read int8 code, reconstruct, bn, fq2 (1 div + LUT), silu
__global__ __launch_bounds__(256) void k_silumm(const signed char* __restrict__ qcv,
    const float* __restrict__ gs, const float* __restrict__ mu, const float* __restrict__ bt,
    unsigned* __restrict__ slots) {
  __shared__ float lutb[256];
  FQ c1, c2; fq_pair(slots, S_CVMN, c1, c2);
  FQ b1q, b2q; fq_pair(slots, S_BNMN, b1q, b2q);
  {
    int i = threadIdx.x;
    float y1 = ((float)(i - 128) - b1q.zp) * b1q.s;
    lutb[i] = fq_apply(y1, b2q);
  }
  __syncthreads();
  float s2 = c2.s, zp2 = c2.zp;
  long i = ((long)blockIdx.x * 256 + threadIdx.x) * 4;
  const long stride = (long)2048 * 256 * 4;
  float lmn = INF, lmx = -INF;
  for (; i < NTOT; i += stride) {
    int f0 = (int)(i & 511);
    c8x4 qv = *(const c8x4*)(qcv + i);
    f32x4 g4 = *(const f32x4*)(gs + f0);
    f32x4 m4 = *(const f32x4*)(mu + f0);
    f32x4 b4 = *(const f32x4*)(bt + f0);
#pragma unroll
    for (int j = 0; j < 4; ++j) {
      float y2 = ((float)(int)qv[j] - zp2) * s2;
      float z = (y2 - m4[j]) * g4[j] + b4[j];
      float z2 = lutb[qidx(z, b1q)];
      float si = z2 * (1.0f / (1.0f + expf(-z2)));
      lmn = fminf(lmn, si); lmx = fmaxf(lmx, si);
    }
  }
  mm_block_atomic(lmn, lmx, slots + S_SIMN, slots + S_SIMX);
}

// A2 build: code -> bn -> fq2(LUT) -> silu -> fq2 via ushort LUT -> bf16 integer
__global__ __launch_bounds__(256) void k_q2(const signed char* __restrict__ qcv,
    const float* __restrict__ gs, const float* __restrict__ mu, const float* __restrict__ bt,
    unsigned short* __restrict__ A2, const unsigned* __restrict__ slots) {
  __shared__ float lutb[256];
  __shared__ unsigned short luts[256];
  FQ c1, c2; fq_pair(slots, S_CVMN, c1, c2);
  FQ b1q, b2q; fq_pair(slots, S_BNMN, b1q, b2q);
  FQ s1q, s2q; fq_pair(slots, S_SIMN, s1q, s2q);
  {
    int i = threadIdx.x;
    float yb = ((float)(i - 128) - b1q.zp) * b1q.s;
    lutb[i] = fq_apply(yb, b2q);
    float ys = ((float)(i - 128) - s1q.zp) * s1q.s;
    luts[i] = to_bf16(fq_qmz(ys, s2q));
  }
  __syncthreads();
  float s2 = c2.s, zp2 = c2.zp;
  long i = ((long)blockIdx.x * 256 + threadIdx.x) * 4;
  const long stride = (long)2048 * 256 * 4;
  for (; i < NTOT; i += stride) {
    int f0 = (int)(i & 511);
    c8x4 qv = *(const c8x4*)(qcv + i);
    f32x4 g4 = *(const f32x4*)(gs + f0);
    f32x4 m4 = *(const f32x4*)(mu + f0);
    f32x4 b4 = *(const f32x4*)(bt + f0);
    s16x4 o;
#pragma unroll
    for (int j = 0; j < 4; ++j) {
      float y2 = ((float)(int)qv[j] - zp2) * s2;
      float z = (y2 - m4[j]) * g4[j] + b4[j];
      float z2 = lutb[qidx(z, b1q)];
      float si = z2 * (1.0f / (1.0f + expf(-z2)));
      o[j] = (short)luts[qidx(si, s1q)];
    }
    *(s16x4*)(A2 + i) = o;
  }
}

__global__ __launch_bounds__(256) void k_final(const float* __restrict__ t18, float* __restrict__ out,
                                               const unsigned* __restrict__ slots) {
  FQ p = fq_params(dec(slots[S_T18MN]), dec(slots[S_T18MX]));
  long i = ((long)blockIdx.x * 256 + threadIdx.x) * 4;
  const long stride = (long)2048 * 256 * 4;
  for (; i < NTOT; i += stride) {
    f32x4 v = *(const f32x4*)(t18 + i);
    f32x4 o;
#pragma unroll
    for (int j = 0; j < 4; ++j) o[j] = fq_apply(v[j], p);
    *(f32x4*)(out + i) = o;
  }
}

extern "C" void kernel_launch(void* const* d_in, const int* in_sizes, int n_in,
                              void* d_out, int out_size, void* d_ws, size_t ws_size,
                              hipStream_t stream) {
  const float* x   = (const float*)d_in[0];
  const float* lns = (const float*)d_in[1];
  const float* lnb = (const float*)d_in[2];
  const float* w1  = (const float*)d_in[3];
  const float* b1  = (const float*)d_in[4];
  const float* dw  = (const float*)d_in[5];
  const float* dwb = (const float*)d_in[6];
  const float* gm  = (const float*)d_in[7];
  const float* bt  = (const float*)d_in[8];
  const float* mu  = (const float*)d_in[9];
  const float* vr  = (const float*)d_in[10];
  const float* w2  = (const float*)d_in[11];
  const float* b2  = (const float*)d_in[12];
  float* out = (float*)d_out;
  char* ws = (char*)d_ws;

  // workspace (aliased lifetimes):
  //  buf0 [0,134MB):   t4 -> conv-out (67MB) -> A2 (33.5MB)
  //  bufB [134,201MB): t7 -> t18
  //  bufD [201,234.5): A1 (33.5MB) -> {q7 int8 (16.78), qcv int8 (16.78)}
  //  then w1q(1MB), w2q(0.5MB), dwq(63.5KB f32), gs(2KB), slots
  const size_t OFF_B = 134217728;
  const size_t OFF_D = OFF_B + 67108864;
  const size_t OFF_W = OFF_D + 33554432;
  const size_t NEED = OFF_W + 1048576 + 524288 + 63488 + 2048 + 256;
  if (ws_size < NEED) return;

  float* buf0 = (float*)ws;
  float* bufB = (float*)(ws + OFF_B);
  unsigned short* bufD = (unsigned short*)(ws + OFF_D);
  signed char* q7  = (signed char*)(ws + OFF_D);
  signed char* qcv = (signed char*)(ws + OFF_D + 16777216);
  unsigned short* A2 = (unsigned short*)ws;
  unsigned short* w1q = (unsigned short*)(ws + OFF_W);
  unsigned short* w2q = (unsigned short*)(ws + OFF_W + 1048576);
  float* dwq = (float*)(ws + OFF_W + 1048576 + 524288);
  float* gs  = (float*)(ws + OFF_W + 1048576 + 524288 + 63488);
  unsigned* slots = (unsigned*)(ws + OFF_W + 1048576 + 524288 + 63488 + 2048);

  k_init<<<1, 512, 0, stream>>>(slots, gm, vr, gs);
  k_wabs<<<3134, 256, 0, stream>>>(w1, w2, dw, slots);
  k_wq<<<3134, 256, 0, stream>>>(w1, w2, dw, w1q, w2q, dwq, slots);
  k_redmm<<<2048, 256, 0, stream>>>(x, slots);
  k_lnmm<<<2048, 256, 0, stream>>>(x, lns, lnb, slots);
  k_qa<<<2048, 256, 0, stream>>>(x, lns, lnb, bufD, slots);
  k_gemm<<<dim3(8, 256), 256, 0, stream>>>(bufD, w1q, b1, buf0, 1024, slots, S_T1MN, S_W1, S_T4MN);
  k_glu<<<2048, 256, 0, stream>>>(buf0, bufB, slots);
  k_qt7<<<2048, 256, 0, stream>>>(bufB, q7, slots);
  k_conv<<<dim3(32, 2, 32), 256, 0, stream>>>(q7, dwq, dwb, buf0, slots);
  k_qcv_bnmm<<<2048, 256, 0, stream>>>(buf0, qcv, gs, mu, bt, slots);
  k_silumm<<<2048, 256, 0, stream>>>(qcv, gs, mu, bt, slots);
  k_q2<<<2048, 256, 0, stream>>>(qcv, gs, mu, bt, A2, slots);
  k_gemm<<<dim3(4, 256), 256, 0, stream>>>(A2, w2q, b2, bufB, 512, slots, S_SIMN, S_W2, S_T18MN);
  k_final<<<2048, 256, 0, stream>>>(bufB, out, slots);
}

// Round 4
// 731.643 us; speedup vs baseline: 1.1256x; 1.0233x over previous
//
#include <hip/hip_runtime.h>
#include <stdint.h>
#include <math.h>

#define INF __builtin_inff()

typedef __attribute__((ext_vector_type(4))) float f32x4;
typedef __attribute__((ext_vector_type(8))) short s16x8;
typedef __attribute__((ext_vector_type(4))) short s16x4;
typedef __attribute__((ext_vector_type(4))) char c8x4;

#define S_XMN 0
#define S_XMX 1
#define S_T1MN 2
#define S_T1MX 3
#define S_T4MN 4
#define S_T4MX 5
#define S_T7MN 6
#define S_T7MX 7
#define S_CVMN 8
#define S_CVMX 9
#define S_BNMN 10
#define S_BNMX 11
#define S_SIMN 12
#define S_SIMX 13
#define S_T18MN 14
#define S_T18MX 15
#define S_W1 16
#define S_W2 17
#define S_DW 18
#define NSLOT 19

#define NTOT 16777216L   // 32*1024*512

__device__ __forceinline__ unsigned enc(float f) {
  unsigned u = __float_as_uint(f);
  return (u & 0x80000000u) ? ~u : (u | 0x80000000u);
}
__device__ __forceinline__ float dec(unsigned k) {
  return (k & 0x80000000u) ? __uint_as_float(k & 0x7FFFFFFFu) : __uint_as_float(~k);
}

struct FQ { float s, zp; };

__device__ __forceinline__ FQ fq_params(float mn_t, float mx_t) {
  float mn = fminf(mn_t, 0.0f), mx = fmaxf(mx_t, 0.0f);
  FQ p;
  p.s = fmaxf((mx - mn) / 255.0f, 1e-8f);
  p.zp = -128.0f - rintf(mn / p.s);
  return p;
}
__device__ __forceinline__ float fq_apply(float x, FQ p) {
  float q = rintf(x / p.s) + p.zp;
  q = fminf(fmaxf(q, -128.0f), 127.0f);
  return (q - p.zp) * p.s;
}
__device__ __forceinline__ float fq_qmz(float x, FQ p) {
  float q = rintf(x / p.s) + p.zp;
  q = fminf(fmaxf(q, -128.0f), 127.0f);
  return q - p.zp;
}
// quantize to LUT index in [0,255]  (ONE true division - matches reference rounding)
__device__ __forceinline__ int qidx(float x, FQ p) {
  float q = rintf(x / p.s) + p.zp;
  q = fminf(fmaxf(q, -128.0f), 127.0f);
  return (int)q + 128;
}
__device__ __forceinline__ int qcode(float x, FQ p) {
  float q = rintf(x / p.s) + p.zp;
  q = fminf(fmaxf(q, -128.0f), 127.0f);
  return (int)q;
}
__device__ __forceinline__ void fq_pair(const unsigned* slots, int idx, FQ& p1, FQ& p2) {
  float mn = dec(slots[idx]), mx = dec(slots[idx + 1]);
  p1 = fq_params(mn, mx);
  float ymn = fq_apply(mn, p1), ymx = fq_apply(mx, p1);
  p2 = fq_params(ymn, ymx);
}
__device__ __forceinline__ unsigned short to_bf16(float v) {
  return (unsigned short)(__float_as_uint(v) >> 16);
}

__device__ __forceinline__ void mm_block_atomic(float mn, float mx, unsigned* smn, unsigned* smx) {
#pragma unroll
  for (int o = 32; o > 0; o >>= 1) {
    mn = fminf(mn, __shfl_down(mn, o, 64));
    mx = fmaxf(mx, __shfl_down(mx, o, 64));
  }
  __shared__ float rmn[16], rmx[16];
  int lane = threadIdx.x & 63, wid = threadIdx.x >> 6;
  int nw = blockDim.x >> 6;
  __syncthreads();
  if (lane == 0) { rmn[wid] = mn; rmx[wid] = mx; }
  __syncthreads();
  if (threadIdx.x == 0) {
    for (int i = 1; i < nw; ++i) { mn = fminf(mn, rmn[i]); mx = fmaxf(mx, rmx[i]); }
    atomicMin(smn, enc(mn));
    atomicMax(smx, enc(mx));
  }
}

__device__ __forceinline__ float wave_sum(float v) {
#pragma unroll
  for (int o = 1; o < 64; o <<= 1) v += __shfl_xor(v, o, 64);
  return v;
}

__global__ void k_init(unsigned* __restrict__ slots, const float* __restrict__ gm,
                       const float* __restrict__ vr, float* __restrict__ gs) {
  int i = threadIdx.x;
  if (i < NSLOT) slots[i] = (i < 16) ? ((i & 1) ? enc(-INF) : enc(INF)) : enc(0.0f);
  gs[i] = gm[i] / sqrtf(vr[i] + 1e-5f);
}

__global__ __launch_bounds__(256) void k_redmm(const float* __restrict__ x, unsigned* __restrict__ slots) {
  long i = ((long)blockIdx.x * 256 + threadIdx.x) * 4;
  const long stride = (long)2048 * 256 * 4;
  float mn = INF, mx = -INF;
  for (; i < NTOT; i += stride) {
    f32x4 v = *(const f32x4*)(x + i);
    mn = fminf(mn, fminf(fminf(v.x, v.y), fminf(v.z, v.w)));
    mx = fmaxf(mx, fmaxf(fmaxf(v.x, v.y), fmaxf(v.z, v.w)));
  }
  mm_block_atomic(mn, mx, slots + S_XMN, slots + S_XMX);
}

__global__ __launch_bounds__(256) void k_wabs(const float* __restrict__ w1, const float* __restrict__ w2,
                                              const float* __restrict__ dw, unsigned* __restrict__ slots) {
  int b = blockIdx.x;
  const float* p; int slot; long base;
  if (b < 2048) { p = w1; slot = S_W1; base = (long)b * 256; }
  else if (b < 3072) { p = w2; slot = S_W2; base = (long)(b - 2048) * 256; }
  else { p = dw; slot = S_DW; base = (long)(b - 3072) * 256; }
  float v = fabsf(p[base + threadIdx.x]);
#pragma unroll
  for (int o = 32; o > 0; o >>= 1) v = fmaxf(v, __shfl_down(v, o, 64));
  __shared__ float r[4];
  int lane = threadIdx.x & 63, wid = threadIdx.x >> 6;
  if (lane == 0) r[wid] = v;
  __syncthreads();
  if (threadIdx.x == 0) {
    v = fmaxf(fmaxf(r[0], r[1]), fmaxf(r[2], r[3]));
    atomicMax(slots + slot, enc(v));
  }
}

__global__ __launch_bounds__(256) void k_wq(const float* __restrict__ w1, const float* __restrict__ w2,
    const float* __restrict__ dw, unsigned short* __restrict__ w1q, unsigned short* __restrict__ w2q,
    float* __restrict__ dwq, const unsigned* __restrict__ slots) {
  int b = blockIdx.x;
  if (b < 2048) {
    float s = fmaxf(dec(slots[S_W1]) / 127.0f, 1e-8f);
    long i = (long)b * 256 + threadIdx.x;
    float q = fminf(fmaxf(rintf(w1[i] / s), -128.0f), 127.0f);
    w1q[i] = to_bf16(q);
  } else if (b < 3072) {
    float s = fmaxf(dec(slots[S_W2]) / 127.0f, 1e-8f);
    long i = (long)(b - 2048) * 256 + threadIdx.x;
    float q = fminf(fmaxf(rintf(w2[i] / s), -128.0f), 127.0f);
    w2q[i] = to_bf16(q);
  } else {
    float s = fmaxf(dec(slots[S_DW]) / 127.0f, 1e-8f);
    long i = (long)(b - 3072) * 256 + threadIdx.x;
    float q = fminf(fmaxf(rintf(dw[i] / s), -128.0f), 127.0f);
    dwq[i] = q;
  }
}

// LN core on decoded fq0 values; MUST be identical arithmetic in both LN passes.
__device__ __forceinline__ void ln_core(float* a, const f32x4& sc0, const f32x4& sc1,
                                        const f32x4& bi0, const f32x4& bi1) {
  float s = a[0] + a[1] + a[2] + a[3] + a[4] + a[5] + a[6] + a[7];
  float mean = wave_sum(s) / 512.0f;
#pragma unroll
  for (int j = 0; j < 8; ++j) a[j] -= mean;
  float l1 = fabsf(a[0]) + fabsf(a[1]) + fabsf(a[2]) + fabsf(a[3])
           + fabsf(a[4]) + fabsf(a[5]) + fabsf(a[6]) + fabsf(a[7]);
  float denom = wave_sum(l1) / 512.0f + 1e-5f;
#pragma unroll
  for (int j = 0; j < 4; ++j) {
    a[j]     = fmaf(a[j] / denom,     sc0[j], bi0[j]);
    a[4 + j] = fmaf(a[4 + j] / denom, sc1[j], bi1[j]);
  }
}

// pass 1: quantize x -> int8 codes (cache), LN min/max (no t1 store)
__global__ __launch_bounds__(256) void k_lnmm(const float* __restrict__ x, const float* __restrict__ lns,
    const float* __restrict__ lnb, signed char* __restrict__ qx, unsigned* __restrict__ slots) {
  FQ p0 = fq_params(dec(slots[S_XMN]), dec(slots[S_XMX]));
  int lane = threadIdx.x & 63, wv = threadIdx.x >> 6;
  long gw = (long)blockIdx.x * 4 + wv;
  f32x4 sc0 = *(const f32x4*)(lns + lane * 4);
  f32x4 sc1 = *(const f32x4*)(lns + 256 + lane * 4);
  f32x4 bi0 = *(const f32x4*)(lnb + lane * 4);
  f32x4 bi1 = *(const f32x4*)(lnb + 256 + lane * 4);
  float lmn = INF, lmx = -INF;
  for (int r = 0; r < 4; ++r) {
    long row = gw + (long)r * 8192;
    f32x4 v0 = *(const f32x4*)(x + row * 512 + lane * 4);
    f32x4 v1 = *(const f32x4*)(x + row * 512 + 256 + lane * 4);
    float a[8];
    c8x4 c0, c1;
#pragma unroll
    for (int j = 0; j < 4; ++j) {
      int q0 = qcode(v0[j], p0), q1 = qcode(v1[j], p0);
      c0[j] = (signed char)q0; c1[j] = (signed char)q1;
      a[j]     = ((float)q0 - p0.zp) * p0.s;
      a[4 + j] = ((float)q1 - p0.zp) * p0.s;
    }
    *(c8x4*)(qx + row * 512 + lane * 4) = c0;
    *(c8x4*)(qx + row * 512 + 256 + lane * 4) = c1;
    ln_core(a, sc0, sc1, bi0, bi1);
#pragma unroll
    for (int j = 0; j < 8; ++j) { lmn = fminf(lmn, a[j]); lmx = fmaxf(lmx, a[j]); }
  }
  mm_block_atomic(lmn, lmx, slots + S_T1MN, slots + S_T1MX);
}

// pass 2: recompute LN from codes (bitwise-identical), double-fq via LUT -> bf16 int A1
__global__ __launch_bounds__(256) void k_qa(const signed char* __restrict__ qx, const float* __restrict__ lns,
    const float* __restrict__ lnb, unsigned short* __restrict__ A1, const unsigned* __restrict__ slots) {
  __shared__ unsigned short lut[256];
  FQ p0 = fq_params(dec(slots[S_XMN]), dec(slots[S_XMX]));
  FQ p1, p2; fq_pair(slots, S_T1MN, p1, p2);
  {
    int i = threadIdx.x;
    float y1 = ((float)(i - 128) - p1.zp) * p1.s;
    lut[i] = to_bf16(fq_qmz(y1, p2));
  }
  __syncthreads();
  int lane = threadIdx.x & 63, wv = threadIdx.x >> 6;
  long gw = (long)blockIdx.x * 4 + wv;
  f32x4 sc0 = *(const f32x4*)(lns + lane * 4);
  f32x4 sc1 = *(const f32x4*)(lns + 256 + lane * 4);
  f32x4 bi0 = *(const f32x4*)(lnb + lane * 4);
  f32x4 bi1 = *(const f32x4*)(lnb + 256 + lane * 4);
  for (int r = 0; r < 4; ++r) {
    long row = gw + (long)r * 8192;
    c8x4 c0 = *(const c8x4*)(qx + row * 512 + lane * 4);
    c8x4 c1 = *(const c8x4*)(qx + row * 512 + 256 + lane * 4);
    float a[8];
#pragma unroll
    for (int j = 0; j < 4; ++j) {
      a[j]     = ((float)(int)c0[j] - p0.zp) * p0.s;
      a[4 + j] = ((float)(int)c1[j] - p0.zp) * p0.s;
    }
    ln_core(a, sc0, sc1, bi0, bi1);
    s16x4 q0, q1;
#pragma unroll
    for (int j = 0; j < 4; ++j) {
      q0[j] = (short)lut[qidx(a[j], p1)];
      q1[j] = (short)lut[qidx(a[4 + j], p1)];
    }
    *(s16x4*)(A1 + row * 512 + lane * 4) = q0;
    *(s16x4*)(A1 + row * 512 + 256 + lane * 4) = q1;
  }
}

// bf16-integer MFMA GEMM with XCD-chunked block remap (A-panel L2 reuse).
__global__ __launch_bounds__(256) void k_gemm(const unsigned short* __restrict__ A,
    const unsigned short* __restrict__ Bm, const float* __restrict__ bias,
    float* __restrict__ C, int N, unsigned* __restrict__ slots, int mmIdx, int wIdx, int omIdx) {
  __shared__ __align__(16) unsigned short lA[128 * 64];
  __shared__ __align__(16) unsigned short lB[128 * 64];
  FQ p1, p2; fq_pair(slots, mmIdx, p1, p2);
  float sw = fmaxf(dec(slots[wIdx]) / 127.0f, 1e-8f);
  float sAB = p2.s * sw;
  int tid = threadIdx.x;
  int nbx = gridDim.x;
  int total = nbx * gridDim.y;
  int id = blockIdx.y * nbx + blockIdx.x;
  int chunk = total >> 3;
  int d = (id & 7) * chunk + (id >> 3);
  int m0 = (d / nbx) * 128, n0 = (d % nbx) * 128;
  int lane = tid & 63, wid = tid >> 6;
  int wm = (wid >> 1) * 64, wn = (wid & 1) * 64;
  const f32x4 fz = {0.0f, 0.0f, 0.0f, 0.0f};
  f32x4 acc[4][4];
#pragma unroll
  for (int mi = 0; mi < 4; ++mi)
#pragma unroll
    for (int ni = 0; ni < 4; ++ni) acc[mi][ni] = fz;
  int sr = tid >> 1;
  int scu = (tid & 1) * 32;
  int swz = (sr & 7) * 8;
  const unsigned short* Ag = A + (long)(m0 + sr) * 512 + scu;
  const unsigned short* Bg = Bm + (long)(n0 + sr) * 512 + scu;
  int fr = lane & 15;
  int fc = (lane >> 4) * 8;
  for (int kt = 0; kt < 8; ++kt) {
    s16x8 ra[4], rb[4];
#pragma unroll
    for (int j = 0; j < 4; ++j) {
      ra[j] = *(const s16x8*)(Ag + kt * 64 + j * 8);
      rb[j] = *(const s16x8*)(Bg + kt * 64 + j * 8);
    }
    __syncthreads();
#pragma unroll
    for (int j = 0; j < 4; ++j) {
      *(s16x8*)&lA[sr * 64 + ((scu + j * 8) ^ swz)] = ra[j];
      *(s16x8*)&lB[sr * 64 + ((scu + j * 8) ^ swz)] = rb[j];
    }
    __syncthreads();
#pragma unroll
    for (int ks = 0; ks < 2; ++ks) {
      s16x8 af[4], bfv[4];
#pragma unroll
      for (int mi = 0; mi < 4; ++mi) {
        int r = wm + mi * 16 + fr;
        af[mi] = *(const s16x8*)&lA[r * 64 + ((ks * 32 + fc) ^ ((r & 7) * 8))];
      }
#pragma unroll
      for (int ni = 0; ni < 4; ++ni) {
        int r = wn + ni * 16 + fr;
        bfv[ni] = *(const s16x8*)&lB[r * 64 + ((ks * 32 + fc) ^ ((r & 7) * 8))];
      }
#pragma unroll
      for (int mi = 0; mi < 4; ++mi)
#pragma unroll
        for (int ni = 0; ni < 4; ++ni)
          acc[mi][ni] = __builtin_amdgcn_mfma_f32_16x16x32_bf16(af[mi], bfv[ni], acc[mi][ni], 0, 0, 0);
    }
  }
  float lmn = INF, lmx = -INF;
  int rb0 = m0 + wm + ((lane >> 4) << 2);
  int cb0 = n0 + wn + (lane & 15);
#pragma unroll
  for (int mi = 0; mi < 4; ++mi) {
#pragma unroll
    for (int ni = 0; ni < 4; ++ni) {
      int col = cb0 + ni * 16;
      float bv = bias[col];
#pragma unroll
      for (int r = 0; r < 4; ++r) {
        int rowi = rb0 + mi * 16 + r;
        float v = sAB * acc[mi][ni][r] + bv;
        C[(long)rowi * N + col] = v;
        lmn = fminf(lmn, v); lmx = fmaxf(lmx, v);
      }
    }
  }
  mm_block_atomic(lmn, lmx, slots + omIdx, slots + omIdx + 1);
}

// GLU: read t4, emit packed (qa,qg); mm(t7) via LUT product (no expf in loop)
__global__ __launch_bounds__(256) void k_glu(const float* __restrict__ t4, unsigned short* __restrict__ pair,
                                             unsigned* __restrict__ slots) {
  __shared__ float lutf[256];
  __shared__ float sglut[256];
  FQ p1, p2; fq_pair(slots, S_T4MN, p1, p2);
  {
    int i = threadIdx.x;
    float y2 = fq_apply(((float)(i - 128) - p1.zp) * p1.s, p2);
    lutf[i] = y2;
    sglut[i] = 1.0f / (1.0f + expf(-y2));
  }
  __syncthreads();
  long i = ((long)blockIdx.x * 256 + threadIdx.x) * 4;
  const long stride = (long)2048 * 256 * 4;
  float lmn = INF, lmx = -INF;
  for (; i < NTOT; i += stride) {
    long r = i >> 9;
    int c = (int)(i & 511);
    const float* pa = t4 + r * 1024 + c;
    f32x4 av = *(const f32x4*)pa;
    f32x4 gv = *(const f32x4*)(pa + 512);
    s16x4 o;
#pragma unroll
    for (int j = 0; j < 4; ++j) {
      int qa = qidx(av[j], p1);
      int qg = qidx(gv[j], p1);
      o[j] = (short)(unsigned short)(qa | (qg << 8));
      float y = lutf[qa] * sglut[qg];
      lmn = fminf(lmn, y); lmx = fmaxf(lmx, y);
    }
    *(s16x4*)(pair + i) = o;
  }
  mm_block_atomic(lmn, lmx, slots + S_T7MN, slots + S_T7MX);
}

// decode pair -> t7 value (identical product) -> double-fq composed int8 code q7
__global__ __launch_bounds__(256) void k_qt7(const unsigned short* __restrict__ pair,
                                             signed char* __restrict__ q7,
                                             const unsigned* __restrict__ slots) {
  __shared__ float lutf[256];
  __shared__ float sglut[256];
  __shared__ signed char lutq[256];
  FQ g1, g2; fq_pair(slots, S_T4MN, g1, g2);
  FQ p1, p2; fq_pair(slots, S_T7MN, p1, p2);
  {
    int i = threadIdx.x;
    float y2 = fq_apply(((float)(i - 128) - g1.zp) * g1.s, g2);
    lutf[i] = y2;
    sglut[i] = 1.0f / (1.0f + expf(-y2));
    float y1 = ((float)(i - 128) - p1.zp) * p1.s;
    float q = fminf(fmaxf(rintf(y1 / p2.s) + p2.zp, -128.0f), 127.0f);
    lutq[i] = (signed char)(int)q;
  }
  __syncthreads();
  long i = ((long)blockIdx.x * 256 + threadIdx.x) * 4;
  const long stride = (long)2048 * 256 * 4;
  for (; i < NTOT; i += stride) {
    s16x4 pv = *(const s16x4*)(pair + i);
    c8x4 o;
#pragma unroll
    for (int j = 0; j < 4; ++j) {
      unsigned u = (unsigned short)pv[j];
      float y = lutf[u & 255] * sglut[u >> 8];
      o[j] = lutq[qidx(y, p1)];
    }
    *(c8x4*)(q7 + i) = o;
  }
}

// depthwise conv: exact integer acc (bitwise-identical across both passes).
// STORE=0: conv min/max only. STORE=1: quantize->qcv + bn min/max.
template<int STORE>
__global__ __launch_bounds__(256) void k_conv(const signed char* __restrict__ q7,
    const float* __restrict__ dwq, const float* __restrict__ dwb,
    signed char* __restrict__ qcv, const float* __restrict__ gs, const float* __restrict__ mu,
    const float* __restrict__ bt, unsigned* __restrict__ slots) {
  __shared__ signed char lutq[256];
  FQ p1, p2; fq_pair(slots, S_T7MN, p1, p2);
  float sdw = fmaxf(dec(slots[S_DW]) / 127.0f, 1e-8f);
  float scv = p2.s * sdw;
  float zp2 = p2.zp;
  FQ c1, c2;
  if (STORE) {
    fq_pair(slots, S_CVMN, c1, c2);
    int i = threadIdx.x;
    float y1 = ((float)(i - 128) - c1.zp) * c1.s;
    float q = fminf(fmaxf(rintf(y1 / c2.s) + c2.zp, -128.0f), 127.0f);
    lutq[i] = (signed char)(int)q;
    __syncthreads();
  }
  int t0 = blockIdx.x * 32;
  int f = blockIdx.y * 256 + threadIdx.x;
  int b = blockIdx.z;
  const signed char* base = q7 + (long)b * 1024 * 512 + f;
  float col[62];
#pragma unroll
  for (int r = 0; r < 62; ++r) {
    int t = t0 - 15 + r;
    float q = 0.0f;
    if ((unsigned)t < 1024u) q = (float)(int)base[(long)t * 512] - zp2;
    col[r] = q;
  }
  float w31[31];
#pragma unroll
  for (int k = 0; k < 31; ++k) w31[k] = dwq[f * 31 + k];
  float bias = dwb[f];
  float gsv = 0.f, muv = 0.f, btv = 0.f;
  if (STORE) { gsv = gs[f]; muv = mu[f]; btv = bt[f]; }
  signed char* orow = STORE ? (qcv + ((long)b * 1024 + t0) * 512 + f) : nullptr;
  float lmn = INF, lmx = -INF;
#pragma unroll
  for (int j = 0; j < 32; ++j) {
    float acc = 0.0f;
#pragma unroll
    for (int k = 0; k < 31; ++k) acc += col[j + k] * w31[k];   // exact integers
    float v = fmaf(scv, acc, bias);
    if (STORE) {
      signed char qc = lutq[qidx(v, c1)];
      orow[(long)j * 512] = qc;
      float y2 = ((float)(int)qc - c2.zp) * c2.s;
      float z = fmaf(y2 - muv, gsv, btv);
      lmn = fminf(lmn, z); lmx = fmaxf(lmx, z);
    } else {
      lmn = fminf(lmn, v); lmx = fmaxf(lmx, v);
    }
  }
  if (STORE) mm_block_atomic(lmn, lmx, slots + S_BNMN, slots + S_BNMX);
  else       mm_block_atomic(lmn, lmx, slots + S_CVMN, slots + S_CVMX);
}

// silu min/max: qcv codes -> bn -> fq2-index -> sillut (no expf in loop)
__global__ __launch_bounds__(256) void k_silumm(const signed char* __restrict__ qcv,
    const float* __restrict__ gs, const float* __restrict__ mu, const float* __restrict__ bt,
    unsigned* __restrict__ slots) {
  __shared__ float sillut[256];
  FQ c1, c2; fq_pair(slots, S_CVMN, c1, c2);
  FQ b1q, b2q; fq_pair(slots, S_BNMN, b1q, b2q);
  {
    int i = threadIdx.x;
    float z2 = fq_apply(((float)(i - 128) - b1q.zp) * b1q.s, b2q);
    sillut[i] = z2 * (1.0f / (1.0f + expf(-z2)));
  }
  __syncthreads();
  float s2 = c2.s, zp2 = c2.zp;
  long i = ((long)blockIdx.x * 256 + threadIdx.x) * 4;
  const long stride = (long)2048 * 256 * 4;
  float lmn = INF, lmx = -INF;
  for (; i < NTOT; i += stride) {
    int f0 = (int)(i & 511);
    c8x4 qv = *(const c8x4*)(qcv + i);
    f32x4 g4 = *(const f32x4*)(gs + f0);
    f32x4 m4 = *(const f32x4*)(mu + f0);
    f32x4 b4 = *(const f32x4*)(bt + f0);
#pragma unroll
    for (int j = 0; j < 4; ++j) {
      float y2 = ((float)(int)qv[j] - zp2) * s2;
      float z = fmaf(y2 - m4[j], g4[j], b4[j]);
      float si = sillut[qidx(z, b1q)];
      lmn = fminf(lmn, si); lmx = fmaxf(lmx, si);
    }
  }
  mm_block_atomic(lmn, lmx, slots + S_SIMN, slots + S_SIMX);
}

// A2 build: qcv code -> bn -> composed LUT (fq2 -> silu -> double-fq -> bf16 int)
__global__ __launch_bounds__(256) void k_q2(const signed char* __restrict__ qcv,
    const float* __restrict__ gs, const float* __restrict__ mu, const float* __restrict__ bt,
    unsigned short* __restrict__ A2, const unsigned* __restrict__ slots) {
  __shared__ unsigned short lutc[256];
  FQ c1, c2; fq_pair(slots, S_CVMN, c1, c2);
  FQ b1q, b2q; fq_pair(slots, S_BNMN, b1q, b2q);
  FQ s1q, s2q; fq_pair(slots, S_SIMN, s1q, s2q);
  {
    int i = threadIdx.x;
    float z2 = fq_apply(((float)(i - 128) - b1q.zp) * b1q.s, b2q);
    float si = z2 * (1.0f / (1.0f + expf(-z2)));
    float ys = ((float)(qidx(si, s1q) - 128) - s1q.zp) * s1q.s;
    lutc[i] = to_bf16(fq_qmz(ys, s2q));
  }
  __syncthreads();
  float s2 = c2.s, zp2 = c2.zp;
  long i = ((long)blockIdx.x * 256 + threadIdx.x) * 4;
  const long stride = (long)2048 * 256 * 4;
  for (; i < NTOT; i += stride) {
    int f0 = (int)(i & 511);
    c8x4 qv = *(const c8x4*)(qcv + i);
    f32x4 g4 = *(const f32x4*)(gs + f0);
    f32x4 m4 = *(const f32x4*)(mu + f0);
    f32x4 b4 = *(const f32x4*)(bt + f0);
    s16x4 o;
#pragma unroll
    for (int j = 0; j < 4; ++j) {
      float y2 = ((float)(int)qv[j] - zp2) * s2;
      float z = fmaf(y2 - m4[j], g4[j], b4[j]);
      o[j] = (short)lutc[qidx(z, b1q)];
    }
    *(s16x4*)(A2 + i) = o;
  }
}

__global__ __launch_bounds__(256) void k_final(const float* __restrict__ t18, float* __restrict__ out,
                                               const unsigned* __restrict__ slots) {
  FQ p = fq_params(dec(slots[S_T18MN]), dec(slots[S_T18MX]));
  long i = ((long)blockIdx.x * 256 + threadIdx.x) * 4;
  const long stride = (long)2048 * 256 * 4;
  for (; i < NTOT; i += stride) {
    f32x4 v = *(const f32x4*)(t18 + i);
    f32x4 o;
#pragma unroll
    for (int j = 0; j < 4; ++j) o[j] = fq_apply(v[j], p);
    *(f32x4*)(out + i) = o;
  }
}

extern "C" void kernel_launch(void* const* d_in, const int* in_sizes, int n_in,
                              void* d_out, int out_size, void* d_ws, size_t ws_size,
                              hipStream_t stream) {
  const float* x   = (const float*)d_in[0];
  const float* lns = (const float*)d_in[1];
  const float* lnb = (const float*)d_in[2];
  const float* w1  = (const float*)d_in[3];
  const float* b1  = (const float*)d_in[4];
  const float* dw  = (const float*)d_in[5];
  const float* dwb = (const float*)d_in[6];
  const float* gm  = (const float*)d_in[7];
  const float* bt  = (const float*)d_in[8];
  const float* mu  = (const float*)d_in[9];
  const float* vr  = (const float*)d_in[10];
  const float* w2  = (const float*)d_in[11];
  const float* b2  = (const float*)d_in[12];
  float* out = (float*)d_out;
  char* ws = (char*)d_ws;

  // workspace (aliased lifetimes):
  //  [0,134M):        t4; after t4 dead: qcv [0,16.7M), A2 [16.7M,50.3M), t18 [50.3M,117.4M)
  //  [134M,167.8M):   A1 (bf16) -> pair (u16)
  //  [167.8M,184.5M): qx (int8) -> q7 (int8)
  //  [184.5M...):     w1q(1MB), w2q(0.5MB), dwq(63.5KB), gs(2KB), slots
  const size_t O_A2  = 16777216;
  const size_t O_T18 = 50331648;
  const size_t O_A1  = 134217728;
  const size_t O_QX  = 167772160;
  const size_t O_WQ  = 184549376;
  const size_t NEED = O_WQ + 1048576 + 524288 + 63488 + 2048 + 256;
  if (ws_size < NEED) return;

  float* t4   = (float*)ws;
  signed char* qcv = (signed char*)ws;
  unsigned short* A2 = (unsigned short*)(ws + O_A2);
  float* t18  = (float*)(ws + O_T18);
  unsigned short* A1 = (unsigned short*)(ws + O_A1);
  unsigned short* pair = (unsigned short*)(ws + O_A1);
  signed char* qx = (signed char*)(ws + O_QX);
  signed char* q7 = (signed char*)(ws + O_QX);
  unsigned short* w1q = (unsigned short*)(ws + O_WQ);
  unsigned short* w2q = (unsigned short*)(ws + O_WQ + 1048576);
  float* dwq = (float*)(ws + O_WQ + 1048576 + 524288);
  float* gs  = (float*)(ws + O_WQ + 1048576 + 524288 + 63488);
  unsigned* slots = (unsigned*)(ws + O_WQ + 1048576 + 524288 + 63488 + 2048);

  k_init<<<1, 512, 0, stream>>>(slots, gm, vr, gs);
  k_wabs<<<3134, 256, 0, stream>>>(w1, w2, dw, slots);
  k_wq<<<3134, 256, 0, stream>>>(w1, w2, dw, w1q, w2q, dwq, slots);
  k_redmm<<<2048, 256, 0, stream>>>(x, slots);
  k_lnmm<<<2048, 256, 0, stream>>>(x, lns, lnb, qx, slots);
  k_qa<<<2048, 256, 0, stream>>>(qx, lns, lnb, A1, slots);
  k_gemm<<<dim3(8, 256), 256, 0, stream>>>(A1, w1q, b1, t4, 1024, slots, S_T1MN, S_W1, S_T4MN);
  k_glu<<<2048, 256, 0, stream>>>(t4, pair, slots);
  k_qt7<<<2048, 256, 0, stream>>>(pair, q7, slots);
  k_conv<0><<<dim3(32, 2, 32), 256, 0, stream>>>(q7, dwq, dwb, nullptr, gs, mu, bt, slots);
  k_conv<1><<<dim3(32, 2, 32), 256, 0, stream>>>(q7, dwq, dwb, qcv, gs, mu, bt, slots);
  k_silumm<<<2048, 256, 0, stream>>>(qcv, gs, mu, bt, slots);
  k_q2<<<2048, 256, 0, stream>>>(qcv, gs, mu, bt, A2, slots);
  k_gemm<<<dim3(4, 256), 256, 0, stream>>>(A2, w2q, b2, t18, 512, slots, S_SIMN, S_W2, S_T18MN);
  k_final<<<2048, 256, 0, stream>>>(t18, out, slots);
}

// Round 5
// 719.705 us; speedup vs baseline: 1.1442x; 1.0166x over previous
//
#include <hip/hip_runtime.h>
#include <stdint.h>
#include <math.h>

#define INF __builtin_inff()

typedef __attribute__((ext_vector_type(4))) float f32x4;
typedef __attribute__((ext_vector_type(8))) short s16x8;
typedef __attribute__((ext_vector_type(4))) short s16x4;
typedef __attribute__((ext_vector_type(4))) char c8x4;

#define S_XMN 0
#define S_XMX 1
#define S_T1MN 2
#define S_T1MX 3
#define S_T4MN 4
#define S_T4MX 5
#define S_T7MN 6
#define S_T7MX 7
#define S_CVMN 8
#define S_CVMX 9
#define S_BNMN 10
#define S_BNMX 11
#define S_SIMN 12
#define S_SIMX 13
#define S_T18MN 14
#define S_T18MX 15
#define S_W1 16
#define S_W2 17
#define S_DW 18
#define NSLOT 19

#define NTOT 16777216L   // 32*1024*512

__device__ __forceinline__ unsigned enc(float f) {
  unsigned u = __float_as_uint(f);
  return (u & 0x80000000u) ? ~u : (u | 0x80000000u);
}
__device__ __forceinline__ float dec(unsigned k) {
  return (k & 0x80000000u) ? __uint_as_float(k & 0x7FFFFFFFu) : __uint_as_float(~k);
}

struct FQ { float s, zp; };

__device__ __forceinline__ FQ fq_params(float mn_t, float mx_t) {
  float mn = fminf(mn_t, 0.0f), mx = fmaxf(mx_t, 0.0f);
  FQ p;
  p.s = fmaxf((mx - mn) / 255.0f, 1e-8f);
  p.zp = -128.0f - rintf(mn / p.s);
  return p;
}
__device__ __forceinline__ float fq_apply(float x, FQ p) {
  float q = rintf(x / p.s) + p.zp;
  q = fminf(fmaxf(q, -128.0f), 127.0f);
  return (q - p.zp) * p.s;
}
__device__ __forceinline__ float fq_qmz(float x, FQ p) {
  float q = rintf(x / p.s) + p.zp;
  q = fminf(fmaxf(q, -128.0f), 127.0f);
  return q - p.zp;
}
// quantize to LUT index in [0,255]  (IEEE div - matches reference rounding)
__device__ __forceinline__ int qidx(float x, FQ p) {
  float q = rintf(x / p.s) + p.zp;
  q = fminf(fmaxf(q, -128.0f), 127.0f);
  return (int)q + 128;
}
__device__ __forceinline__ int qcode(float x, FQ p) {
  float q = rintf(x / p.s) + p.zp;
  q = fminf(fmaxf(q, -128.0f), 127.0f);
  return (int)q;
}
__device__ __forceinline__ void fq_pair(const unsigned* slots, int idx, FQ& p1, FQ& p2) {
  float mn = dec(slots[idx]), mx = dec(slots[idx + 1]);
  p1 = fq_params(mn, mx);
  float ymn = fq_apply(mn, p1), ymx = fq_apply(mx, p1);
  p2 = fq_params(ymn, ymx);
}
__device__ __forceinline__ unsigned short to_bf16(float v) {
  return (unsigned short)(__float_as_uint(v) >> 16);
}

// async global->LDS, 16B per lane; LDS dest is wave-uniform base + lane*16
__device__ __forceinline__ void gload_lds16(const void* g, void* l) {
  __builtin_amdgcn_global_load_lds(
      (const __attribute__((address_space(1))) unsigned int*)g,
      (__attribute__((address_space(3))) unsigned int*)l, 16, 0, 0);
}

__device__ __forceinline__ void mm_block_atomic(float mn, float mx, unsigned* smn, unsigned* smx) {
#pragma unroll
  for (int o = 32; o > 0; o >>= 1) {
    mn = fminf(mn, __shfl_down(mn, o, 64));
    mx = fmaxf(mx, __shfl_down(mx, o, 64));
  }
  __shared__ float rmn[16], rmx[16];
  int lane = threadIdx.x & 63, wid = threadIdx.x >> 6;
  int nw = blockDim.x >> 6;
  __syncthreads();
  if (lane == 0) { rmn[wid] = mn; rmx[wid] = mx; }
  __syncthreads();
  if (threadIdx.x == 0) {
    for (int i = 1; i < nw; ++i) { mn = fminf(mn, rmn[i]); mx = fmaxf(mx, rmx[i]); }
    atomicMin(smn, enc(mn));
    atomicMax(smx, enc(mx));
  }
}

__device__ __forceinline__ float wave_sum(float v) {
#pragma unroll
  for (int o = 1; o < 64; o <<= 1) v += __shfl_xor(v, o, 64);
  return v;
}

__global__ void k_init(unsigned* __restrict__ slots, const float* __restrict__ gm,
                       const float* __restrict__ vr, float* __restrict__ gs) {
  int i = threadIdx.x;
  if (i < NSLOT) slots[i] = (i < 16) ? ((i & 1) ? enc(-INF) : enc(INF)) : enc(0.0f);
  gs[i] = gm[i] / sqrtf(vr[i] + 1e-5f);
}

__global__ __launch_bounds__(256) void k_redmm(const float* __restrict__ x, unsigned* __restrict__ slots) {
  long i = ((long)blockIdx.x * 256 + threadIdx.x) * 4;
  const long stride = (long)2048 * 256 * 4;
  float mn = INF, mx = -INF;
  for (; i < NTOT; i += stride) {
    f32x4 v = *(const f32x4*)(x + i);
    mn = fminf(mn, fminf(fminf(v.x, v.y), fminf(v.z, v.w)));
    mx = fmaxf(mx, fmaxf(fmaxf(v.x, v.y), fmaxf(v.z, v.w)));
  }
  mm_block_atomic(mn, mx, slots + S_XMN, slots + S_XMX);
}

__global__ __launch_bounds__(256) void k_wabs(const float* __restrict__ w1, const float* __restrict__ w2,
                                              const float* __restrict__ dw, unsigned* __restrict__ slots) {
  int b = blockIdx.x;
  const float* p; int slot; long base;
  if (b < 2048) { p = w1; slot = S_W1; base = (long)b * 256; }
  else if (b < 3072) { p = w2; slot = S_W2; base = (long)(b - 2048) * 256; }
  else { p = dw; slot = S_DW; base = (long)(b - 3072) * 256; }
  float v = fabsf(p[base + threadIdx.x]);
#pragma unroll
  for (int o = 32; o > 0; o >>= 1) v = fmaxf(v, __shfl_down(v, o, 64));
  __shared__ float r[4];
  int lane = threadIdx.x & 63, wid = threadIdx.x >> 6;
  if (lane == 0) r[wid] = v;
  __syncthreads();
  if (threadIdx.x == 0) {
    v = fmaxf(fmaxf(r[0], r[1]), fmaxf(r[2], r[3]));
    atomicMax(slots + slot, enc(v));
  }
}

// weight quant; dw written TRANSPOSED: dwqT[k*512 + f]
__global__ __launch_bounds__(256) void k_wq(const float* __restrict__ w1, const float* __restrict__ w2,
    const float* __restrict__ dw, unsigned short* __restrict__ w1q, unsigned short* __restrict__ w2q,
    float* __restrict__ dwqT, const unsigned* __restrict__ slots) {
  int b = blockIdx.x;
  if (b < 2048) {
    float s = fmaxf(dec(slots[S_W1]) / 127.0f, 1e-8f);
    long i = (long)b * 256 + threadIdx.x;
    float q = fminf(fmaxf(rintf(w1[i] / s), -128.0f), 127.0f);
    w1q[i] = to_bf16(q);
  } else if (b < 3072) {
    float s = fmaxf(dec(slots[S_W2]) / 127.0f, 1e-8f);
    long i = (long)(b - 2048) * 256 + threadIdx.x;
    float q = fminf(fmaxf(rintf(w2[i] / s), -128.0f), 127.0f);
    w2q[i] = to_bf16(q);
  } else {
    float s = fmaxf(dec(slots[S_DW]) / 127.0f, 1e-8f);
    int i = (b - 3072) * 256 + threadIdx.x;   // i < 15872 = 512*31
    int f = i / 31, k = i % 31;
    float q = fminf(fmaxf(rintf(dw[i] / s), -128.0f), 127.0f);
    dwqT[k * 512 + f] = q;
  }
}

// LN core on decoded fq0 values; MUST be identical arithmetic in both LN passes.
__device__ __forceinline__ void ln_core(float* a, const f32x4& sc0, const f32x4& sc1,
                                        const f32x4& bi0, const f32x4& bi1) {
  float s = a[0] + a[1] + a[2] + a[3] + a[4] + a[5] + a[6] + a[7];
  float mean = wave_sum(s) / 512.0f;
#pragma unroll
  for (int j = 0; j < 8; ++j) a[j] -= mean;
  float l1 = fabsf(a[0]) + fabsf(a[1]) + fabsf(a[2]) + fabsf(a[3])
           + fabsf(a[4]) + fabsf(a[5]) + fabsf(a[6]) + fabsf(a[7]);
  float denom = wave_sum(l1) / 512.0f + 1e-5f;
#pragma unroll
  for (int j = 0; j < 4; ++j) {
    a[j]     = fmaf(a[j] / denom,     sc0[j], bi0[j]);
    a[4 + j] = fmaf(a[4 + j] / denom, sc1[j], bi1[j]);
  }
}

// pass 1: quantize x -> int8 codes (cache), LN min/max (no t1 store)
__global__ __launch_bounds__(256) void k_lnmm(const float* __restrict__ x, const float* __restrict__ lns,
    const float* __restrict__ lnb, signed char* __restrict__ qx, unsigned* __restrict__ slots) {
  FQ p0 = fq_params(dec(slots[S_XMN]), dec(slots[S_XMX]));
  int lane = threadIdx.x & 63, wv = threadIdx.x >> 6;
  long gw = (long)blockIdx.x * 4 + wv;
  f32x4 sc0 = *(const f32x4*)(lns + lane * 4);
  f32x4 sc1 = *(const f32x4*)(lns + 256 + lane * 4);
  f32x4 bi0 = *(const f32x4*)(lnb + lane * 4);
  f32x4 bi1 = *(const f32x4*)(lnb + 256 + lane * 4);
  float lmn = INF, lmx = -INF;
  for (int r = 0; r < 4; ++r) {
    long row = gw + (long)r * 8192;
    f32x4 v0 = *(const f32x4*)(x + row * 512 + lane * 4);
    f32x4 v1 = *(const f32x4*)(x + row * 512 + 256 + lane * 4);
    float a[8];
    c8x4 c0, c1;
#pragma unroll
    for (int j = 0; j < 4; ++j) {
      int q0 = qcode(v0[j], p0), q1 = qcode(v1[j], p0);
      c0[j] = (signed char)q0; c1[j] = (signed char)q1;
      a[j]     = ((float)q0 - p0.zp) * p0.s;
      a[4 + j] = ((float)q1 - p0.zp) * p0.s;
    }
    *(c8x4*)(qx + row * 512 + lane * 4) = c0;
    *(c8x4*)(qx + row * 512 + 256 + lane * 4) = c1;
    ln_core(a, sc0, sc1, bi0, bi1);
#pragma unroll
    for (int j = 0; j < 8; ++j) { lmn = fminf(lmn, a[j]); lmx = fmaxf(lmx, a[j]); }
  }
  mm_block_atomic(lmn, lmx, slots + S_T1MN, slots + S_T1MX);
}

// pass 2: recompute LN from codes (bitwise-identical), double-fq via LUT -> bf16 int A1
__global__ __launch_bounds__(256) void k_qa(const signed char* __restrict__ qx, const float* __restrict__ lns,
    const float* __restrict__ lnb, unsigned short* __restrict__ A1, const unsigned* __restrict__ slots) {
  __shared__ unsigned short lut[256];
  FQ p0 = fq_params(dec(slots[S_XMN]), dec(slots[S_XMX]));
  FQ p1, p2; fq_pair(slots, S_T1MN, p1, p2);
  {
    int i = threadIdx.x;
    float y1 = ((float)(i - 128) - p1.zp) * p1.s;
    lut[i] = to_bf16(fq_qmz(y1, p2));
  }
  __syncthreads();
  int lane = threadIdx.x & 63, wv = threadIdx.x >> 6;
  long gw = (long)blockIdx.x * 4 + wv;
  f32x4 sc0 = *(const f32x4*)(lns + lane * 4);
  f32x4 sc1 = *(const f32x4*)(lns + 256 + lane * 4);
  f32x4 bi0 = *(const f32x4*)(lnb + lane * 4);
  f32x4 bi1 = *(const f32x4*)(lnb + 256 + lane * 4);
  for (int r = 0; r < 4; ++r) {
    long row = gw + (long)r * 8192;
    c8x4 c0 = *(const c8x4*)(qx + row * 512 + lane * 4);
    c8x4 c1 = *(const c8x4*)(qx + row * 512 + 256 + lane * 4);
    float a[8];
#pragma unroll
    for (int j = 0; j < 4; ++j) {
      a[j]     = ((float)(int)c0[j] - p0.zp) * p0.s;
      a[4 + j] = ((float)(int)c1[j] - p0.zp) * p0.s;
    }
    ln_core(a, sc0, sc1, bi0, bi1);
    s16x4 q0, q1;
#pragma unroll
    for (int j = 0; j < 4; ++j) {
      q0[j] = (short)lut[qidx(a[j], p1)];
      q1[j] = (short)lut[qidx(a[4 + j], p1)];
    }
    *(s16x4*)(A1 + row * 512 + lane * 4) = q0;
    *(s16x4*)(A1 + row * 512 + 256 + lane * 4) = q1;
  }
}

// bf16-integer MFMA GEMM; XCD-chunked remap; global_load_lds staging with
// pre-swizzled SOURCE column (LDS dest linear; LDS contents identical to R4).
__global__ __launch_bounds__(256) void k_gemm(const unsigned short* __restrict__ A,
    const unsigned short* __restrict__ Bm, const float* __restrict__ bias,
    float* __restrict__ C, int N, unsigned* __restrict__ slots, int mmIdx, int wIdx, int omIdx) {
  __shared__ __align__(16) unsigned short lA[128 * 64];
  __shared__ __align__(16) unsigned short lB[128 * 64];
  FQ p1, p2; fq_pair(slots, mmIdx, p1, p2);
  float sw = fmaxf(dec(slots[wIdx]) / 127.0f, 1e-8f);
  float sAB = p2.s * sw;
  int tid = threadIdx.x;
  int nbx = gridDim.x;
  int total = nbx * gridDim.y;
  int id = blockIdx.y * nbx + blockIdx.x;
  int chunk = total >> 3;
  int d = (id & 7) * chunk + (id >> 3);
  int m0 = (d / nbx) * 128, n0 = (d % nbx) * 128;
  int lane = tid & 63, w = tid >> 6;
  int wm = (w >> 1) * 64, wn = (w & 1) * 64;
  const f32x4 fz = {0.0f, 0.0f, 0.0f, 0.0f};
  f32x4 acc[4][4];
#pragma unroll
  for (int mi = 0; mi < 4; ++mi)
#pragma unroll
    for (int ni = 0; ni < 4; ++ni) acc[mi][ni] = fz;
  // staging geometry: per wave w, call i covers rows w*32+i*8 .. +8, 16B/lane
  int r8 = lane >> 3;                 // row within 8-row group
  int c8 = (lane & 7) * 8;            // u16 col of this lane's 16B chunk
  int srcc = c8 ^ (r8 * 8);           // pre-swizzled source column
  const unsigned short* Abase[4];
  const unsigned short* Bbase[4];
#pragma unroll
  for (int i = 0; i < 4; ++i) {
    int row = w * 32 + i * 8 + r8;
    Abase[i] = A + (long)(m0 + row) * 512 + srcc;
    Bbase[i] = Bm + (long)(n0 + row) * 512 + srcc;
  }
  char* lAc = (char*)lA;
  char* lBc = (char*)lB;
  int fr = lane & 15;
  int fc = (lane >> 4) * 8;
  for (int kt = 0; kt < 8; ++kt) {
    if (kt) __syncthreads();          // previous compute done before overwrite
#pragma unroll
    for (int i = 0; i < 4; ++i) {
      gload_lds16(Abase[i] + kt * 64, lAc + (w * 4 + i) * 1024);
      gload_lds16(Bbase[i] + kt * 64, lBc + (w * 4 + i) * 1024);
    }
    __syncthreads();                  // drains vmcnt -> LDS tile ready
#pragma unroll
    for (int ks = 0; ks < 2; ++ks) {
      s16x8 af[4], bfv[4];
#pragma unroll
      for (int mi = 0; mi < 4; ++mi) {
        int r = wm + mi * 16 + fr;
        af[mi] = *(const s16x8*)&lA[r * 64 + ((ks * 32 + fc) ^ ((r & 7) * 8))];
      }
#pragma unroll
      for (int ni = 0; ni < 4; ++ni) {
        int r = wn + ni * 16 + fr;
        bfv[ni] = *(const s16x8*)&lB[r * 64 + ((ks * 32 + fc) ^ ((r & 7) * 8))];
      }
#pragma unroll
      for (int mi = 0; mi < 4; ++mi)
#pragma unroll
        for (int ni = 0; ni < 4; ++ni)
          acc[mi][ni] = __builtin_amdgcn_mfma_f32_16x16x32_bf16(af[mi], bfv[ni], acc[mi][ni], 0, 0, 0);
    }
  }
  float lmn = INF, lmx = -INF;
  int rb0 = m0 + wm + ((lane >> 4) << 2);
  int cb0 = n0 + wn + (lane & 15);
#pragma unroll
  for (int mi = 0; mi < 4; ++mi) {
#pragma unroll
    for (int ni = 0; ni < 4; ++ni) {
      int col = cb0 + ni * 16;
      float bv = bias[col];
#pragma unroll
      for (int r = 0; r < 4; ++r) {
        int rowi = rb0 + mi * 16 + r;
        float v = sAB * acc[mi][ni][r] + bv;
        C[(long)rowi * N + col] = v;
        lmn = fminf(lmn, v); lmx = fmaxf(lmx, v);
      }
    }
  }
  mm_block_atomic(lmn, lmx, slots + omIdx, slots + omIdx + 1);
}

// GLU: read t4, emit packed (qa,qg); mm(t7) via LUT product (no expf in loop)
__global__ __launch_bounds__(256) void k_glu(const float* __restrict__ t4, unsigned short* __restrict__ pair,
                                             unsigned* __restrict__ slots) {
  __shared__ float lutf[256];
  __shared__ float sglut[256];
  FQ p1, p2; fq_pair(slots, S_T4MN, p1, p2);
  {
    int i = threadIdx.x;
    float y2 = fq_apply(((float)(i - 128) - p1.zp) * p1.s, p2);
    lutf[i] = y2;
    sglut[i] = 1.0f / (1.0f + expf(-y2));
  }
  __syncthreads();
  long i = ((long)blockIdx.x * 256 + threadIdx.x) * 4;
  const long stride = (long)2048 * 256 * 4;
  float lmn = INF, lmx = -INF;
  for (; i < NTOT; i += stride) {
    long r = i >> 9;
    int c = (int)(i & 511);
    const float* pa = t4 + r * 1024 + c;
    f32x4 av = *(const f32x4*)pa;
    f32x4 gv = *(const f32x4*)(pa + 512);
    s16x4 o;
#pragma unroll
    for (int j = 0; j < 4; ++j) {
      int qa = qidx(av[j], p1);
      int qg = qidx(gv[j], p1);
      o[j] = (short)(unsigned short)(qa | (qg << 8));
      float y = lutf[qa] * sglut[qg];
      lmn = fminf(lmn, y); lmx = fmaxf(lmx, y);
    }
    *(s16x4*)(pair + i) = o;
  }
  mm_block_atomic(lmn, lmx, slots + S_T7MN, slots + S_T7MX);
}

// decode pair -> t7 value (identical product) -> double-fq composed int8 code q7
__global__ __launch_bounds__(256) void k_qt7(const unsigned short* __restrict__ pair,
                                             signed char* __restrict__ q7,
                                             const unsigned* __restrict__ slots) {
  __shared__ float lutf[256];
  __shared__ float sglut[256];
  __shared__ signed char lutq[256];
  FQ g1, g2; fq_pair(slots, S_T4MN, g1, g2);
  FQ p1, p2; fq_pair(slots, S_T7MN, p1, p2);
  {
    int i = threadIdx.x;
    float y2 = fq_apply(((float)(i - 128) - g1.zp) * g1.s, g2);
    lutf[i] = y2;
    sglut[i] = 1.0f / (1.0f + expf(-y2));
    float y1 = ((float)(i - 128) - p1.zp) * p1.s;
    float q = fminf(fmaxf(rintf(y1 / p2.s) + p2.zp, -128.0f), 127.0f);
    lutq[i] = (signed char)(int)q;
  }
  __syncthreads();
  long i = ((long)blockIdx.x * 256 + threadIdx.x) * 4;
  const long stride = (long)2048 * 256 * 4;
  for (; i < NTOT; i += stride) {
    s16x4 pv = *(const s16x4*)(pair + i);
    c8x4 o;
#pragma unroll
    for (int j = 0; j < 4; ++j) {
      unsigned u = (unsigned short)pv[j];
      float y = lutf[u & 255] * sglut[u >> 8];
      o[j] = lutq[qidx(y, p1)];
    }
    *(c8x4*)(q7 + i) = o;
  }
}

// depthwise conv: exact integer acc, 4 independent chains (reassociation exact for ints).
// STORE=0: conv min/max only. STORE=1: quantize->qcv + bn min/max.
template<int STORE>
__global__ __launch_bounds__(256, 1) void k_conv(const signed char* __restrict__ q7,
    const float* __restrict__ dwqT, const float* __restrict__ dwb,
    signed char* __restrict__ qcv, const float* __restrict__ gs, const float* __restrict__ mu,
    const float* __restrict__ bt, unsigned* __restrict__ slots) {
  __shared__ signed char lutq[256];
  FQ p1, p2; fq_pair(slots, S_T7MN, p1, p2);
  float sdw = fmaxf(dec(slots[S_DW]) / 127.0f, 1e-8f);
  float scv = p2.s * sdw;
  float zp2 = p2.zp;
  FQ c1, c2;
  if (STORE) {
    fq_pair(slots, S_CVMN, c1, c2);
    int i = threadIdx.x;
    float y1 = ((float)(i - 128) - c1.zp) * c1.s;
    float q = fminf(fmaxf(rintf(y1 / c2.s) + c2.zp, -128.0f), 127.0f);
    lutq[i] = (signed char)(int)q;
    __syncthreads();
  }
  int t0 = blockIdx.x * 32;
  int f = blockIdx.y * 256 + threadIdx.x;
  int b = blockIdx.z;
  const signed char* base = q7 + (long)b * 1024 * 512 + f;
  float col[62];
#pragma unroll
  for (int r = 0; r < 62; ++r) {
    int t = t0 - 15 + r;
    float q = 0.0f;
    if ((unsigned)t < 1024u) q = (float)(int)base[(long)t * 512] - zp2;
    col[r] = q;
  }
  float wv[31];
#pragma unroll
  for (int k = 0; k < 31; ++k) wv[k] = dwqT[k * 512 + f];
  float bias = dwb[f];
  float gsv = 0.f, muv = 0.f, btv = 0.f;
  if (STORE) { gsv = gs[f]; muv = mu[f]; btv = bt[f]; }
  signed char* orow = STORE ? (qcv + ((long)b * 1024 + t0) * 512 + f) : nullptr;
  float lmn = INF, lmx = -INF;
#pragma unroll
  for (int j = 0; j < 32; ++j) {
    float a0 = 0.f, a1 = 0.f, a2 = 0.f, a3 = 0.f;   // 4 indep chains; exact ints
#pragma unroll
    for (int k = 0; k < 28; k += 4) {
      a0 += col[j + k]     * wv[k];
      a1 += col[j + k + 1] * wv[k + 1];
      a2 += col[j + k + 2] * wv[k + 2];
      a3 += col[j + k + 3] * wv[k + 3];
    }
    a0 += col[j + 28] * wv[28];
    a1 += col[j + 29] * wv[29];
    a2 += col[j + 30] * wv[30];
    float acc = (a0 + a1) + (a2 + a3);
    float v = fmaf(scv, acc, bias);
    if (STORE) {
      signed char qc = lutq[qidx(v, c1)];
      orow[(long)j * 512] = qc;
      float y2 = ((float)(int)qc - c2.zp) * c2.s;
      float z = fmaf(y2 - muv, gsv, btv);
      lmn = fminf(lmn, z); lmx = fmaxf(lmx, z);
    } else {
      lmn = fminf(lmn, v); lmx = fmaxf(lmx, v);
    }
  }
  if (STORE) mm_block_atomic(lmn, lmx, slots + S_BNMN, slots + S_BNMX);
  else       mm_block_atomic(lmn, lmx, slots + S_CVMN, slots + S_CVMX);
}

// silu min/max: qcv codes -> bn -> fq2-index -> sillut (no expf in loop)
__global__ __launch_bounds__(256) void k_silumm(const signed char* __restrict__ qcv,
    const float* __restrict__ gs, const float* __restrict__ mu, const float* __restrict__ bt,
    unsigned* __restrict__ slots) {
  __shared__ float sillut[256];
  FQ c1, c2; fq_pair(slots, S_CVMN, c1, c2);
  FQ b1q, b2q; fq_pair(slots, S_BNMN, b1q, b2q);
  {
    int i = threadIdx.x;
    float z2 = fq_apply(((float)(i - 128) - b1q.zp) * b1q.s, b2q);
    sillut[i] = z2 * (1.0f / (1.0f + expf(-z2)));
  }
  __syncthreads();
  float s2 = c2.s, zp2 = c2.zp;
  long i = ((long)blockIdx.x * 256 + threadIdx.x) * 4;
  const long stride = (long)2048 * 256 * 4;
  float lmn = INF, lmx = -INF;
  for (; i < NTOT; i += stride) {
    int f0 = (int)(i & 511);
    c8x4 qv = *(const c8x4*)(qcv + i);
    f32x4 g4 = *(const f32x4*)(gs + f0);
    f32x4 m4 = *(const f32x4*)(mu + f0);
    f32x4 b4 = *(const f32x4*)(bt + f0);
#pragma unroll
    for (int j = 0; j < 4; ++j) {
      float y2 = ((float)(int)qv[j] - zp2) * s2;
      float z = fmaf(y2 - m4[j], g4[j], b4[j]);
      float si = sillut[qidx(z, b1q)];
      lmn = fminf(lmn, si); lmx = fmaxf(lmx, si);
    }
  }
  mm_block_atomic(lmn, lmx, slots + S_SIMN, slots + S_SIMX);
}

// A2 build: qcv code -> bn -> composed LUT (fq2 -> silu -> double-fq -> bf16 int)
__global__ __launch_bounds__(256) void k_q2(const signed char* __restrict__ qcv,
    const float* __restrict__ gs, const float* __restrict__ mu, const float* __restrict__ bt,
    unsigned short* __restrict__ A2, const unsigned* __restrict__ slots) {
  __shared__ unsigned short lutc[256];
  FQ c1, c2; fq_pair(slots, S_CVMN, c1, c2);
  FQ b1q, b2q; fq_pair(slots, S_BNMN, b1q, b2q);
  FQ s1q, s2q; fq_pair(slots, S_SIMN, s1q, s2q);
  {
    int i = threadIdx.x;
    float z2 = fq_apply(((float)(i - 128) - b1q.zp) * b1q.s, b2q);
    float si = z2 * (1.0f / (1.0f + expf(-z2)));
    float ys = ((float)(qidx(si, s1q) - 128) - s1q.zp) * s1q.s;
    lutc[i] = to_bf16(fq_qmz(ys, s2q));
  }
  __syncthreads();
  float s2 = c2.s, zp2 = c2.zp;
  long i = ((long)blockIdx.x * 256 + threadIdx.x) * 4;
  const long stride = (long)2048 * 256 * 4;
  for (; i < NTOT; i += stride) {
    int f0 = (int)(i & 511);
    c8x4 qv = *(const c8x4*)(qcv + i);
    f32x4 g4 = *(const f32x4*)(gs + f0);
    f32x4 m4 = *(const f32x4*)(mu + f0);
    f32x4 b4 = *(const f32x4*)(bt + f0);
    s16x4 o;
#pragma unroll
    for (int j = 0; j < 4; ++j) {
      float y2 = ((float)(int)qv[j] - zp2) * s2;
      float z = fmaf(y2 - m4[j], g4[j], b4[j]);
      o[j] = (short)lutc[qidx(z, b1q)];
    }
    *(s16x4*)(A2 + i) = o;
  }
}

__global__ __launch_bounds__(256) void k_final(const float* __restrict__ t18, float* __restrict__ out,
                                               const unsigned* __restrict__ slots) {
  FQ p = fq_params(dec(slots[S_T18MN]), dec(slots[S_T18MX]));
  long i = ((long)blockIdx.x * 256 + threadIdx.x) * 4;
  const long stride = (long)2048 * 256 * 4;
  for (; i < NTOT; i += stride) {
    f32x4 v = *(const f32x4*)(t18 + i);
    f32x4 o;
#pragma unroll
    for (int j = 0; j < 4; ++j) o[j] = fq_apply(v[j], p);
    *(f32x4*)(out + i) = o;
  }
}

extern "C" void kernel_launch(void* const* d_in, const int* in_sizes, int n_in,
                              void* d_out, int out_size, void* d_ws, size_t ws_size,
                              hipStream_t stream) {
  const float* x   = (const float*)d_in[0];
  const float* lns = (const float*)d_in[1];
  const float* lnb = (const float*)d_in[2];
  const float* w1  = (const float*)d_in[3];
  const float* b1  = (const float*)d_in[4];
  const float* dw  = (const float*)d_in[5];
  const float* dwb = (const float*)d_in[6];
  const float* gm  = (const float*)d_in[7];
  const float* bt  = (const float*)d_in[8];
  const float* mu  = (const float*)d_in[9];
  const float* vr  = (const float*)d_in[10];
  const float* w2  = (const float*)d_in[11];
  const float* b2  = (const float*)d_in[12];
  float* out = (float*)d_out;
  char* ws = (char*)d_ws;

  // workspace (aliased lifetimes):
  //  [0,134M):        t4; after t4 dead: qcv [0,16.7M), A2 [16.7M,50.3M), t18 [50.3M,117.4M)
  //  [134M,167.8M):   A1 (bf16) -> pair (u16)
  //  [167.8M,184.5M): qx (int8) -> q7 (int8)
  //  [184.5M...):     w1q(1MB), w2q(0.5MB), dwqT(63.5KB), gs(2KB), slots
  const size_t O_A2  = 16777216;
  const size_t O_T18 = 50331648;
  const size_t O_A1  = 134217728;
  const size_t O_QX  = 167772160;
  const size_t O_WQ  = 184549376;
  const size_t NEED = O_WQ + 1048576 + 524288 + 63488 + 2048 + 256;
  if (ws_size < NEED) return;

  float* t4   = (float*)ws;
  signed char* qcv = (signed char*)ws;
  unsigned short* A2 = (unsigned short*)(ws + O_A2);
  float* t18  = (float*)(ws + O_T18);
  unsigned short* A1 = (unsigned short*)(ws + O_A1);
  unsigned short* pair = (unsigned short*)(ws + O_A1);
  signed char* qx = (signed char*)(ws + O_QX);
  signed char* q7 = (signed char*)(ws + O_QX);
  unsigned short* w1q = (unsigned short*)(ws + O_WQ);
  unsigned short* w2q = (unsigned short*)(ws + O_WQ + 1048576);
  float* dwqT = (float*)(ws + O_WQ + 1048576 + 524288);
  float* gs  = (float*)(ws + O_WQ + 1048576 + 524288 + 63488);
  unsigned* slots = (unsigned*)(ws + O_WQ + 1048576 + 524288 + 63488 + 2048);

  k_init<<<1, 512, 0, stream>>>(slots, gm, vr, gs);
  k_wabs<<<3134, 256, 0, stream>>>(w1, w2, dw, slots);
  k_wq<<<3134, 256, 0, stream>>>(w1, w2, dw, w1q, w2q, dwqT, slots);
  k_redmm<<<2048, 256, 0, stream>>>(x, slots);
  k_lnmm<<<2048, 256, 0, stream>>>(x, lns, lnb, qx, slots);
  k_qa<<<2048, 256, 0, stream>>>(qx, lns, lnb, A1, slots);
  k_gemm<<<dim3(8, 256), 256, 0, stream>>>(A1, w1q, b1, t4, 1024, slots, S_T1MN, S_W1, S_T4MN);
  k_glu<<<2048, 256, 0, stream>>>(t4, pair, slots);
  k_qt7<<<2048, 256, 0, stream>>>(pair, q7, slots);
  k_conv<0><<<dim3(32, 2, 32), 256, 0, stream>>>(q7, dwqT, dwb, nullptr, gs, mu, bt, slots);
  k_conv<1><<<dim3(32, 2, 32), 256, 0, stream>>>(q7, dwqT, dwb, qcv, gs, mu, bt, slots);
  k_silumm<<<2048, 256, 0, stream>>>(qcv, gs, mu, bt, slots);
  k_q2<<<2048, 256, 0, stream>>>(qcv, gs, mu, bt, A2, slots);
  k_gemm<<<dim3(4, 256), 256, 0, stream>>>(A2, w2q, b2, t18, 512, slots, S_SIMN, S_W2, S_T18MN);
  k_final<<<2048, 256, 0, stream>>>(t18, out, slots);
}

// Round 6
// 715.651 us; speedup vs baseline: 1.1507x; 1.0057x over previous
//
#include <hip/hip_runtime.h>
#include <stdint.h>
#include <math.h>

#define INF __builtin_inff()

typedef __attribute__((ext_vector_type(4))) float f32x4;
typedef __attribute__((ext_vector_type(8))) short s16x8;
typedef __attribute__((ext_vector_type(4))) short s16x4;
typedef __attribute__((ext_vector_type(4))) char c8x4;

#define S_XMN 0
#define S_XMX 1
#define S_T1MN 2
#define S_T1MX 3
#define S_T4MN 4
#define S_T4MX 5
#define S_T7MN 6
#define S_T7MX 7
#define S_CVMN 8
#define S_CVMX 9
#define S_BNMN 10
#define S_BNMX 11
#define S_SIMN 12
#define S_SIMX 13
#define S_T18MN 14
#define S_T18MX 15
#define S_W1 16
#define S_W2 17
#define S_DW 18
#define NSLOT 19

#define NTOT 16777216L   // 32*1024*512

__device__ __forceinline__ unsigned enc(float f) {
  unsigned u = __float_as_uint(f);
  return (u & 0x80000000u) ? ~u : (u | 0x80000000u);
}
__device__ __forceinline__ float dec(unsigned k) {
  return (k & 0x80000000u) ? __uint_as_float(k & 0x7FFFFFFFu) : __uint_as_float(~k);
}

struct FQ { float s, zp; };

__device__ __forceinline__ FQ fq_params(float mn_t, float mx_t) {
  float mn = fminf(mn_t, 0.0f), mx = fmaxf(mx_t, 0.0f);
  FQ p;
  p.s = fmaxf((mx - mn) / 255.0f, 1e-8f);
  p.zp = -128.0f - rintf(mn / p.s);
  return p;
}
__device__ __forceinline__ float fq_apply(float x, FQ p) {
  float q = rintf(x / p.s) + p.zp;
  q = fminf(fmaxf(q, -128.0f), 127.0f);
  return (q - p.zp) * p.s;
}
__device__ __forceinline__ float fq_qmz(float x, FQ p) {
  float q = rintf(x / p.s) + p.zp;
  q = fminf(fmaxf(q, -128.0f), 127.0f);
  return q - p.zp;
}
// quantize to LUT index in [0,255]  (IEEE div - matches reference rounding)
__device__ __forceinline__ int qidx(float x, FQ p) {
  float q = rintf(x / p.s) + p.zp;
  q = fminf(fmaxf(q, -128.0f), 127.0f);
  return (int)q + 128;
}
__device__ __forceinline__ int qcode(float x, FQ p) {
  float q = rintf(x / p.s) + p.zp;
  q = fminf(fmaxf(q, -128.0f), 127.0f);
  return (int)q;
}
__device__ __forceinline__ void fq_pair(const unsigned* slots, int idx, FQ& p1, FQ& p2) {
  float mn = dec(slots[idx]), mx = dec(slots[idx + 1]);
  p1 = fq_params(mn, mx);
  float ymn = fq_apply(mn, p1), ymx = fq_apply(mx, p1);
  p2 = fq_params(ymn, ymx);
}
__device__ __forceinline__ unsigned short to_bf16(float v) {
  return (unsigned short)(__float_as_uint(v) >> 16);
}

// async global->LDS, 16B per lane; LDS dest is wave-uniform base + lane*16
__device__ __forceinline__ void gload_lds16(const void* g, void* l) {
  __builtin_amdgcn_global_load_lds(
      (const __attribute__((address_space(1))) unsigned int*)g,
      (__attribute__((address_space(3))) unsigned int*)l, 16, 0, 0);
}

__device__ __forceinline__ void mm_block_atomic(float mn, float mx, unsigned* smn, unsigned* smx) {
#pragma unroll
  for (int o = 32; o > 0; o >>= 1) {
    mn = fminf(mn, __shfl_down(mn, o, 64));
    mx = fmaxf(mx, __shfl_down(mx, o, 64));
  }
  __shared__ float rmn[16], rmx[16];
  int lane = threadIdx.x & 63, wid = threadIdx.x >> 6;
  int nw = blockDim.x >> 6;
  __syncthreads();
  if (lane == 0) { rmn[wid] = mn; rmx[wid] = mx; }
  __syncthreads();
  if (threadIdx.x == 0) {
    for (int i = 1; i < nw; ++i) { mn = fminf(mn, rmn[i]); mx = fmaxf(mx, rmx[i]); }
    atomicMin(smn, enc(mn));
    atomicMax(smx, enc(mx));
  }
}

__device__ __forceinline__ float wave_sum(float v) {
#pragma unroll
  for (int o = 1; o < 64; o <<= 1) v += __shfl_xor(v, o, 64);
  return v;
}

__global__ void k_init(unsigned* __restrict__ slots, const float* __restrict__ gm,
                       const float* __restrict__ vr, float* __restrict__ gs) {
  int i = threadIdx.x;
  if (i < NSLOT) slots[i] = (i < 16) ? ((i & 1) ? enc(-INF) : enc(INF)) : enc(0.0f);
  gs[i] = gm[i] / sqrtf(vr[i] + 1e-5f);
}

__global__ __launch_bounds__(256) void k_redmm(const float* __restrict__ x, unsigned* __restrict__ slots) {
  long i = ((long)blockIdx.x * 256 + threadIdx.x) * 4;
  const long stride = (long)2048 * 256 * 4;
  float mn = INF, mx = -INF;
  for (; i < NTOT; i += stride) {
    f32x4 v = *(const f32x4*)(x + i);
    mn = fminf(mn, fminf(fminf(v.x, v.y), fminf(v.z, v.w)));
    mx = fmaxf(mx, fmaxf(fmaxf(v.x, v.y), fmaxf(v.z, v.w)));
  }
  mm_block_atomic(mn, mx, slots + S_XMN, slots + S_XMX);
}

__global__ __launch_bounds__(256) void k_wabs(const float* __restrict__ w1, const float* __restrict__ w2,
                                              const float* __restrict__ dw, unsigned* __restrict__ slots) {
  int b = blockIdx.x;
  const float* p; int slot; long base;
  if (b < 2048) { p = w1; slot = S_W1; base = (long)b * 256; }
  else if (b < 3072) { p = w2; slot = S_W2; base = (long)(b - 2048) * 256; }
  else { p = dw; slot = S_DW; base = (long)(b - 3072) * 256; }
  float v = fabsf(p[base + threadIdx.x]);
#pragma unroll
  for (int o = 32; o > 0; o >>= 1) v = fmaxf(v, __shfl_down(v, o, 64));
  __shared__ float r[4];
  int lane = threadIdx.x & 63, wid = threadIdx.x >> 6;
  if (lane == 0) r[wid] = v;
  __syncthreads();
  if (threadIdx.x == 0) {
    v = fmaxf(fmaxf(r[0], r[1]), fmaxf(r[2], r[3]));
    atomicMax(slots + slot, enc(v));
  }
}

// weight quant; dw written TRANSPOSED: dwqT[k*512 + f]
__global__ __launch_bounds__(256) void k_wq(const float* __restrict__ w1, const float* __restrict__ w2,
    const float* __restrict__ dw, unsigned short* __restrict__ w1q, unsigned short* __restrict__ w2q,
    float* __restrict__ dwqT, const unsigned* __restrict__ slots) {
  int b = blockIdx.x;
  if (b < 2048) {
    float s = fmaxf(dec(slots[S_W1]) / 127.0f, 1e-8f);
    long i = (long)b * 256 + threadIdx.x;
    float q = fminf(fmaxf(rintf(w1[i] / s), -128.0f), 127.0f);
    w1q[i] = to_bf16(q);
  } else if (b < 3072) {
    float s = fmaxf(dec(slots[S_W2]) / 127.0f, 1e-8f);
    long i = (long)(b - 2048) * 256 + threadIdx.x;
    float q = fminf(fmaxf(rintf(w2[i] / s), -128.0f), 127.0f);
    w2q[i] = to_bf16(q);
  } else {
    float s = fmaxf(dec(slots[S_DW]) / 127.0f, 1e-8f);
    int i = (b - 3072) * 256 + threadIdx.x;   // i < 15872 = 512*31
    int f = i / 31, k = i % 31;
    float q = fminf(fmaxf(rintf(dw[i] / s), -128.0f), 127.0f);
    dwqT[k * 512 + f] = q;
  }
}

// LN core on decoded fq0 values; MUST be identical arithmetic in both LN passes.
__device__ __forceinline__ void ln_core(float* a, const f32x4& sc0, const f32x4& sc1,
                                        const f32x4& bi0, const f32x4& bi1) {
  float s = a[0] + a[1] + a[2] + a[3] + a[4] + a[5] + a[6] + a[7];
  float mean = wave_sum(s) / 512.0f;
#pragma unroll
  for (int j = 0; j < 8; ++j) a[j] -= mean;
  float l1 = fabsf(a[0]) + fabsf(a[1]) + fabsf(a[2]) + fabsf(a[3])
           + fabsf(a[4]) + fabsf(a[5]) + fabsf(a[6]) + fabsf(a[7]);
  float denom = wave_sum(l1) / 512.0f + 1e-5f;
#pragma unroll
  for (int j = 0; j < 4; ++j) {
    a[j]     = fmaf(a[j] / denom,     sc0[j], bi0[j]);
    a[4 + j] = fmaf(a[4 + j] / denom, sc1[j], bi1[j]);
  }
}

// pass 1: quantize x -> int8 codes (cache), LN min/max (no t1 store)
__global__ __launch_bounds__(256) void k_lnmm(const float* __restrict__ x, const float* __restrict__ lns,
    const float* __restrict__ lnb, signed char* __restrict__ qx, unsigned* __restrict__ slots) {
  FQ p0 = fq_params(dec(slots[S_XMN]), dec(slots[S_XMX]));
  int lane = threadIdx.x & 63, wv = threadIdx.x >> 6;
  long gw = (long)blockIdx.x * 4 + wv;
  f32x4 sc0 = *(const f32x4*)(lns + lane * 4);
  f32x4 sc1 = *(const f32x4*)(lns + 256 + lane * 4);
  f32x4 bi0 = *(const f32x4*)(lnb + lane * 4);
  f32x4 bi1 = *(const f32x4*)(lnb + 256 + lane * 4);
  float lmn = INF, lmx = -INF;
  for (int r = 0; r < 4; ++r) {
    long row = gw + (long)r * 8192;
    f32x4 v0 = *(const f32x4*)(x + row * 512 + lane * 4);
    f32x4 v1 = *(const f32x4*)(x + row * 512 + 256 + lane * 4);
    float a[8];
    c8x4 c0, c1;
#pragma unroll
    for (int j = 0; j < 4; ++j) {
      int q0 = qcode(v0[j], p0), q1 = qcode(v1[j], p0);
      c0[j] = (signed char)q0; c1[j] = (signed char)q1;
      a[j]     = ((float)q0 - p0.zp) * p0.s;
      a[4 + j] = ((float)q1 - p0.zp) * p0.s;
    }
    *(c8x4*)(qx + row * 512 + lane * 4) = c0;
    *(c8x4*)(qx + row * 512 + 256 + lane * 4) = c1;
    ln_core(a, sc0, sc1, bi0, bi1);
#pragma unroll
    for (int j = 0; j < 8; ++j) { lmn = fminf(lmn, a[j]); lmx = fmaxf(lmx, a[j]); }
  }
  mm_block_atomic(lmn, lmx, slots + S_T1MN, slots + S_T1MX);
}

// pass 2: recompute LN from codes (bitwise-identical), double-fq via LUT -> bf16 int A1
__global__ __launch_bounds__(256) void k_qa(const signed char* __restrict__ qx, const float* __restrict__ lns,
    const float* __restrict__ lnb, unsigned short* __restrict__ A1, const unsigned* __restrict__ slots) {
  __shared__ unsigned short lut[256];
  FQ p0 = fq_params(dec(slots[S_XMN]), dec(slots[S_XMX]));
  FQ p1, p2; fq_pair(slots, S_T1MN, p1, p2);
  {
    int i = threadIdx.x;
    float y1 = ((float)(i - 128) - p1.zp) * p1.s;
    lut[i] = to_bf16(fq_qmz(y1, p2));
  }
  __syncthreads();
  int lane = threadIdx.x & 63, wv = threadIdx.x >> 6;
  long gw = (long)blockIdx.x * 4 + wv;
  f32x4 sc0 = *(const f32x4*)(lns + lane * 4);
  f32x4 sc1 = *(const f32x4*)(lns + 256 + lane * 4);
  f32x4 bi0 = *(const f32x4*)(lnb + lane * 4);
  f32x4 bi1 = *(const f32x4*)(lnb + 256 + lane * 4);
  for (int r = 0; r < 4; ++r) {
    long row = gw + (long)r * 8192;
    c8x4 c0 = *(const c8x4*)(qx + row * 512 + lane * 4);
    c8x4 c1 = *(const c8x4*)(qx + row * 512 + 256 + lane * 4);
    float a[8];
#pragma unroll
    for (int j = 0; j < 4; ++j) {
      a[j]     = ((float)(int)c0[j] - p0.zp) * p0.s;
      a[4 + j] = ((float)(int)c1[j] - p0.zp) * p0.s;
    }
    ln_core(a, sc0, sc1, bi0, bi1);
    s16x4 q0, q1;
#pragma unroll
    for (int j = 0; j < 4; ++j) {
      q0[j] = (short)lut[qidx(a[j], p1)];
      q1[j] = (short)lut[qidx(a[4 + j], p1)];
    }
    *(s16x4*)(A1 + row * 512 + lane * 4) = q0;
    *(s16x4*)(A1 + row * 512 + 256 + lane * 4) = q1;
  }
}

// bf16-integer MFMA GEMM; XCD-chunked remap; global_load_lds staging with
// pre-swizzled SOURCE column (LDS dest linear).
__global__ __launch_bounds__(256) void k_gemm(const unsigned short* __restrict__ A,
    const unsigned short* __restrict__ Bm, const float* __restrict__ bias,
    float* __restrict__ C, int N, unsigned* __restrict__ slots, int mmIdx, int wIdx, int omIdx) {
  __shared__ __align__(16) unsigned short lA[128 * 64];
  __shared__ __align__(16) unsigned short lB[128 * 64];
  FQ p1, p2; fq_pair(slots, mmIdx, p1, p2);
  float sw = fmaxf(dec(slots[wIdx]) / 127.0f, 1e-8f);
  float sAB = p2.s * sw;
  int tid = threadIdx.x;
  int nbx = gridDim.x;
  int total = nbx * gridDim.y;
  int id = blockIdx.y * nbx + blockIdx.x;
  int chunk = total >> 3;
  int d = (id & 7) * chunk + (id >> 3);
  int m0 = (d / nbx) * 128, n0 = (d % nbx) * 128;
  int lane = tid & 63, w = tid >> 6;
  int wm = (w >> 1) * 64, wn = (w & 1) * 64;
  const f32x4 fz = {0.0f, 0.0f, 0.0f, 0.0f};
  f32x4 acc[4][4];
#pragma unroll
  for (int mi = 0; mi < 4; ++mi)
#pragma unroll
    for (int ni = 0; ni < 4; ++ni) acc[mi][ni] = fz;
  // staging geometry: per wave w, call i covers rows w*32+i*8 .. +8, 16B/lane
  int r8 = lane >> 3;                 // row within 8-row group
  int c8 = (lane & 7) * 8;            // u16 col of this lane's 16B chunk
  int srcc = c8 ^ (r8 * 8);           // pre-swizzled source column
  const unsigned short* Abase[4];
  const unsigned short* Bbase[4];
#pragma unroll
  for (int i = 0; i < 4; ++i) {
    int row = w * 32 + i * 8 + r8;
    Abase[i] = A + (long)(m0 + row) * 512 + srcc;
    Bbase[i] = Bm + (long)(n0 + row) * 512 + srcc;
  }
  char* lAc = (char*)lA;
  char* lBc = (char*)lB;
  int fr = lane & 15;
  int fc = (lane >> 4) * 8;
  for (int kt = 0; kt < 8; ++kt) {
    if (kt) __syncthreads();          // previous compute done before overwrite
#pragma unroll
    for (int i = 0; i < 4; ++i) {
      gload_lds16(Abase[i] + kt * 64, lAc + (w * 4 + i) * 1024);
      gload_lds16(Bbase[i] + kt * 64, lBc + (w * 4 + i) * 1024);
    }
    __syncthreads();                  // drains vmcnt -> LDS tile ready
#pragma unroll
    for (int ks = 0; ks < 2; ++ks) {
      s16x8 af[4], bfv[4];
#pragma unroll
      for (int mi = 0; mi < 4; ++mi) {
        int r = wm + mi * 16 + fr;
        af[mi] = *(const s16x8*)&lA[r * 64 + ((ks * 32 + fc) ^ ((r & 7) * 8))];
      }
#pragma unroll
      for (int ni = 0; ni < 4; ++ni) {
        int r = wn + ni * 16 + fr;
        bfv[ni] = *(const s16x8*)&lB[r * 64 + ((ks * 32 + fc) ^ ((r & 7) * 8))];
      }
#pragma unroll
      for (int mi = 0; mi < 4; ++mi)
#pragma unroll
        for (int ni = 0; ni < 4; ++ni)
          acc[mi][ni] = __builtin_amdgcn_mfma_f32_16x16x32_bf16(af[mi], bfv[ni], acc[mi][ni], 0, 0, 0);
    }
  }
  float lmn = INF, lmx = -INF;
  int rb0 = m0 + wm + ((lane >> 4) << 2);
  int cb0 = n0 + wn + (lane & 15);
#pragma unroll
  for (int mi = 0; mi < 4; ++mi) {
#pragma unroll
    for (int ni = 0; ni < 4; ++ni) {
      int col = cb0 + ni * 16;
      float bv = bias[col];
#pragma unroll
      for (int r = 0; r < 4; ++r) {
        int rowi = rb0 + mi * 16 + r;
        float v = sAB * acc[mi][ni][r] + bv;
        C[(long)rowi * N + col] = v;
        lmn = fminf(lmn, v); lmx = fmaxf(lmx, v);
      }
    }
  }
  mm_block_atomic(lmn, lmx, slots + omIdx, slots + omIdx + 1);
}

// GLU: read t4, emit packed (qa,qg); mm(t7) via LUT product (no expf in loop)
__global__ __launch_bounds__(256) void k_glu(const float* __restrict__ t4, unsigned short* __restrict__ pair,
                                             unsigned* __restrict__ slots) {
  __shared__ float lutf[256];
  __shared__ float sglut[256];
  FQ p1, p2; fq_pair(slots, S_T4MN, p1, p2);
  {
    int i = threadIdx.x;
    float y2 = fq_apply(((float)(i - 128) - p1.zp) * p1.s, p2);
    lutf[i] = y2;
    sglut[i] = 1.0f / (1.0f + expf(-y2));
  }
  __syncthreads();
  long i = ((long)blockIdx.x * 256 + threadIdx.x) * 4;
  const long stride = (long)2048 * 256 * 4;
  float lmn = INF, lmx = -INF;
  for (; i < NTOT; i += stride) {
    long r = i >> 9;
    int c = (int)(i & 511);
    const float* pa = t4 + r * 1024 + c;
    f32x4 av = *(const f32x4*)pa;
    f32x4 gv = *(const f32x4*)(pa + 512);
    s16x4 o;
#pragma unroll
    for (int j = 0; j < 4; ++j) {
      int qa = qidx(av[j], p1);
      int qg = qidx(gv[j], p1);
      o[j] = (short)(unsigned short)(qa | (qg << 8));
      float y = lutf[qa] * sglut[qg];
      lmn = fminf(lmn, y); lmx = fmaxf(lmx, y);
    }
    *(s16x4*)(pair + i) = o;
  }
  mm_block_atomic(lmn, lmx, slots + S_T7MN, slots + S_T7MX);
}

// decode pair -> t7 value (identical product) -> double-fq composed int8 code q7
__global__ __launch_bounds__(256) void k_qt7(const unsigned short* __restrict__ pair,
                                             signed char* __restrict__ q7,
                                             const unsigned* __restrict__ slots) {
  __shared__ float lutf[256];
  __shared__ float sglut[256];
  __shared__ signed char lutq[256];
  FQ g1, g2; fq_pair(slots, S_T4MN, g1, g2);
  FQ p1, p2; fq_pair(slots, S_T7MN, p1, p2);
  {
    int i = threadIdx.x;
    float y2 = fq_apply(((float)(i - 128) - g1.zp) * g1.s, g2);
    lutf[i] = y2;
    sglut[i] = 1.0f / (1.0f + expf(-y2));
    float y1 = ((float)(i - 128) - p1.zp) * p1.s;
    float q = fminf(fmaxf(rintf(y1 / p2.s) + p2.zp, -128.0f), 127.0f);
    lutq[i] = (signed char)(int)q;
  }
  __syncthreads();
  long i = ((long)blockIdx.x * 256 + threadIdx.x) * 4;
  const long stride = (long)2048 * 256 * 4;
  for (; i < NTOT; i += stride) {
    s16x4 pv = *(const s16x4*)(pair + i);
    c8x4 o;
#pragma unroll
    for (int j = 0; j < 4; ++j) {
      unsigned u = (unsigned short)pv[j];
      float y = lutf[u & 255] * sglut[u >> 8];
      o[j] = lutq[qidx(y, p1)];
    }
    *(c8x4*)(q7 + i) = o;
  }
}

// depthwise conv: OUTPUT-SPACE accumulation — o[32] static accumulators, window
// value streamed (no col[] array -> no scratch). Exact integer sums; identical
// across both passes (same template, same op order).
// STORE=0: conv min/max only. STORE=1: quantize->qcv + bn min/max.
template<int STORE>
__global__ __launch_bounds__(256) void k_conv(const signed char* __restrict__ q7,
    const float* __restrict__ dwqT, const float* __restrict__ dwb,
    signed char* __restrict__ qcv, const float* __restrict__ gs, const float* __restrict__ mu,
    const float* __restrict__ bt, unsigned* __restrict__ slots) {
  __shared__ signed char lutq[256];
  FQ p1, p2; fq_pair(slots, S_T7MN, p1, p2);
  float sdw = fmaxf(dec(slots[S_DW]) / 127.0f, 1e-8f);
  float scv = p2.s * sdw;
  float zp2 = p2.zp;
  FQ c1, c2;
  if (STORE) {
    fq_pair(slots, S_CVMN, c1, c2);
    int i = threadIdx.x;
    float y1 = ((float)(i - 128) - c1.zp) * c1.s;
    float q = fminf(fmaxf(rintf(y1 / c2.s) + c2.zp, -128.0f), 127.0f);
    lutq[i] = (signed char)(int)q;
    __syncthreads();
  }
  int t0 = blockIdx.x * 32;
  int f = blockIdx.y * 256 + threadIdx.x;
  int b = blockIdx.z;
  const signed char* base = q7 + (long)b * 1024 * 512 + f;
  float wv[31];
#pragma unroll
  for (int k = 0; k < 31; ++k) wv[k] = dwqT[k * 512 + f];
  float o[32];
#pragma unroll
  for (int j = 0; j < 32; ++j) o[j] = 0.0f;
#pragma unroll
  for (int r = 0; r < 62; ++r) {
    int t = t0 - 15 + r;
    float q = 0.0f;
    if ((unsigned)t < 1024u) q = (float)(int)base[(long)t * 512] - zp2;
    const int jlo = (r - 30 < 0) ? 0 : r - 30;
    const int jhi = (r < 31) ? r : 31;
#pragma unroll
    for (int j = jlo; j <= jhi; ++j)
      o[j] += q * wv[r - j];          // all indices compile-time
  }
  float bias = dwb[f];
  float gsv = 0.f, muv = 0.f, btv = 0.f;
  if (STORE) { gsv = gs[f]; muv = mu[f]; btv = bt[f]; }
  signed char* orow = STORE ? (qcv + ((long)b * 1024 + t0) * 512 + f) : nullptr;
  float lmn = INF, lmx = -INF;
#pragma unroll
  for (int j = 0; j < 32; ++j) {
    float v = fmaf(scv, o[j], bias);
    if (STORE) {
      signed char qc = lutq[qidx(v, c1)];
      orow[(long)j * 512] = qc;
      float y2 = ((float)(int)qc - c2.zp) * c2.s;
      float z = fmaf(y2 - muv, gsv, btv);
      lmn = fminf(lmn, z); lmx = fmaxf(lmx, z);
    } else {
      lmn = fminf(lmn, v); lmx = fmaxf(lmx, v);
    }
  }
  if (STORE) mm_block_atomic(lmn, lmx, slots + S_BNMN, slots + S_BNMX);
  else       mm_block_atomic(lmn, lmx, slots + S_CVMN, slots + S_CVMX);
}

// silu min/max: qcv codes -> bn -> fq2-index -> sillut (no expf in loop)
__global__ __launch_bounds__(256) void k_silumm(const signed char* __restrict__ qcv,
    const float* __restrict__ gs, const float* __restrict__ mu, const float* __restrict__ bt,
    unsigned* __restrict__ slots) {
  __shared__ float sillut[256];
  FQ c1, c2; fq_pair(slots, S_CVMN, c1, c2);
  FQ b1q, b2q; fq_pair(slots, S_BNMN, b1q, b2q);
  {
    int i = threadIdx.x;
    float z2 = fq_apply(((float)(i - 128) - b1q.zp) * b1q.s, b2q);
    sillut[i] = z2 * (1.0f / (1.0f + expf(-z2)));
  }
  __syncthreads();
  float s2 = c2.s, zp2 = c2.zp;
  long i = ((long)blockIdx.x * 256 + threadIdx.x) * 4;
  const long stride = (long)2048 * 256 * 4;
  float lmn = INF, lmx = -INF;
  for (; i < NTOT; i += stride) {
    int f0 = (int)(i & 511);
    c8x4 qv = *(const c8x4*)(qcv + i);
    f32x4 g4 = *(const f32x4*)(gs + f0);
    f32x4 m4 = *(const f32x4*)(mu + f0);
    f32x4 b4 = *(const f32x4*)(bt + f0);
#pragma unroll
    for (int j = 0; j < 4; ++j) {
      float y2 = ((float)(int)qv[j] - zp2) * s2;
      float z = fmaf(y2 - m4[j], g4[j], b4[j]);
      float si = sillut[qidx(z, b1q)];
      lmn = fminf(lmn, si); lmx = fmaxf(lmx, si);
    }
  }
  mm_block_atomic(lmn, lmx, slots + S_SIMN, slots + S_SIMX);
}

// A2 build: qcv code -> bn -> composed LUT (fq2 -> silu -> double-fq -> bf16 int)
__global__ __launch_bounds__(256) void k_q2(const signed char* __restrict__ qcv,
    const float* __restrict__ gs, const float* __restrict__ mu, const float* __restrict__ bt,
    unsigned short* __restrict__ A2, const unsigned* __restrict__ slots) {
  __shared__ unsigned short lutc[256];
  FQ c1, c2; fq_pair(slots, S_CVMN, c1, c2);
  FQ b1q, b2q; fq_pair(slots, S_BNMN, b1q, b2q);
  FQ s1q, s2q; fq_pair(slots, S_SIMN, s1q, s2q);
  {
    int i = threadIdx.x;
    float z2 = fq_apply(((float)(i - 128) - b1q.zp) * b1q.s, b2q);
    float si = z2 * (1.0f / (1.0f + expf(-z2)));
    float ys = ((float)(qidx(si, s1q) - 128) - s1q.zp) * s1q.s;
    lutc[i] = to_bf16(fq_qmz(ys, s2q));
  }
  __syncthreads();
  float s2 = c2.s, zp2 = c2.zp;
  long i = ((long)blockIdx.x * 256 + threadIdx.x) * 4;
  const long stride = (long)2048 * 256 * 4;
  for (; i < NTOT; i += stride) {
    int f0 = (int)(i & 511);
    c8x4 qv = *(const c8x4*)(qcv + i);
    f32x4 g4 = *(const f32x4*)(gs + f0);
    f32x4 m4 = *(const f32x4*)(mu + f0);
    f32x4 b4 = *(const f32x4*)(bt + f0);
    s16x4 o;
#pragma unroll
    for (int j = 0; j < 4; ++j) {
      float y2 = ((float)(int)qv[j] - zp2) * s2;
      float z = fmaf(y2 - m4[j], g4[j], b4[j]);
      o[j] = (short)lutc[qidx(z, b1q)];
    }
    *(s16x4*)(A2 + i) = o;
  }
}

__global__ __launch_bounds__(256) void k_final(const float* __restrict__ t18, float* __restrict__ out,
                                               const unsigned* __restrict__ slots) {
  FQ p = fq_params(dec(slots[S_T18MN]), dec(slots[S_T18MX]));
  long i = ((long)blockIdx.x * 256 + threadIdx.x) * 4;
  const long stride = (long)2048 * 256 * 4;
  for (; i < NTOT; i += stride) {
    f32x4 v = *(const f32x4*)(t18 + i);
    f32x4 o;
#pragma unroll
    for (int j = 0; j < 4; ++j) o[j] = fq_apply(v[j], p);
    *(f32x4*)(out + i) = o;
  }
}

extern "C" void kernel_launch(void* const* d_in, const int* in_sizes, int n_in,
                              void* d_out, int out_size, void* d_ws, size_t ws_size,
                              hipStream_t stream) {
  const float* x   = (const float*)d_in[0];
  const float* lns = (const float*)d_in[1];
  const float* lnb = (const float*)d_in[2];
  const float* w1  = (const float*)d_in[3];
  const float* b1  = (const float*)d_in[4];
  const float* dw  = (const float*)d_in[5];
  const float* dwb = (const float*)d_in[6];
  const float* gm  = (const float*)d_in[7];
  const float* bt  = (const float*)d_in[8];
  const float* mu  = (const float*)d_in[9];
  const float* vr  = (const float*)d_in[10];
  const float* w2  = (const float*)d_in[11];
  const float* b2  = (const float*)d_in[12];
  float* out = (float*)d_out;
  char* ws = (char*)d_ws;

  // workspace (aliased lifetimes):
  //  [0,134M):        t4; after t4 dead: qcv [0,16.7M), A2 [16.7M,50.3M), t18 [50.3M,117.4M)
  //  [134M,167.8M):   A1 (bf16) -> pair (u16)
  //  [167.8M,184.5M): qx (int8) -> q7 (int8)
  //  [184.5M...):     w1q(1MB), w2q(0.5MB), dwqT(63.5KB), gs(2KB), slots
  const size_t O_A2  = 16777216;
  const size_t O_T18 = 50331648;
  const size_t O_A1  = 134217728;
  const size_t O_QX  = 167772160;
  const size_t O_WQ  = 184549376;
  const size_t NEED = O_WQ + 1048576 + 524288 + 63488 + 2048 + 256;
  if (ws_size < NEED) return;

  float* t4   = (float*)ws;
  signed char* qcv = (signed char*)ws;
  unsigned short* A2 = (unsigned short*)(ws + O_A2);
  float* t18  = (float*)(ws + O_T18);
  unsigned short* A1 = (unsigned short*)(ws + O_A1);
  unsigned short* pair = (unsigned short*)(ws + O_A1);
  signed char* qx = (signed char*)(ws + O_QX);
  signed char* q7 = (signed char*)(ws + O_QX);
  unsigned short* w1q = (unsigned short*)(ws + O_WQ);
  unsigned short* w2q = (unsigned short*)(ws + O_WQ + 1048576);
  float* dwqT = (float*)(ws + O_WQ + 1048576 + 524288);
  float* gs  = (float*)(ws + O_WQ + 1048576 + 524288 + 63488);
  unsigned* slots = (unsigned*)(ws + O_WQ + 1048576 + 524288 + 63488 + 2048);

  k_init<<<1, 512, 0, stream>>>(slots, gm, vr, gs);
  k_wabs<<<3134, 256, 0, stream>>>(w1, w2, dw, slots);
  k_wq<<<3134, 256, 0, stream>>>(w1, w2, dw, w1q, w2q, dwqT, slots);
  k_redmm<<<2048, 256, 0, stream>>>(x, slots);
  k_lnmm<<<2048, 256, 0, stream>>>(x, lns, lnb, qx, slots);
  k_qa<<<2048, 256, 0, stream>>>(qx, lns, lnb, A1, slots);
  k_gemm<<<dim3(8, 256), 256, 0, stream>>>(A1, w1q, b1, t4, 1024, slots, S_T1MN, S_W1, S_T4MN);
  k_glu<<<2048, 256, 0, stream>>>(t4, pair, slots);
  k_qt7<<<2048, 256, 0, stream>>>(pair, q7, slots);
  k_conv<0><<<dim3(32, 2, 32), 256, 0, stream>>>(q7, dwqT, dwb, nullptr, gs, mu, bt, slots);
  k_conv<1><<<dim3(32, 2, 32), 256, 0, stream>>>(q7, dwqT, dwb, qcv, gs, mu, bt, slots);
  k_silumm<<<2048, 256, 0, stream>>>(qcv, gs, mu, bt, slots);
  k_q2<<<2048, 256, 0, stream>>>(qcv, gs, mu, bt, A2, slots);
  k_gemm<<<dim3(4, 256), 256, 0, stream>>>(A2, w2q, b2, t18, 512, slots, S_SIMN, S_W2, S_T18MN);
  k_final<<<2048, 256, 0, stream>>>(t18, out, slots);
}